// Round 1
// baseline (2465.672 us; speedup 1.0000x reference)
//
#include <hip/hip_runtime.h>
#include <hip/hip_bf16.h>

// Problem constants
#define B_   32
#define L_   512
#define D_   512
#define H_   8
#define NL_  6
#define F_   2048
#define C_   9
#define HD_  64
#define MTOK 16384   // B_*L_

typedef __bf16 bf16x8 __attribute__((ext_vector_type(8)));
typedef __bf16 bf16x4 __attribute__((ext_vector_type(4)));
typedef float  f32x4  __attribute__((ext_vector_type(4)));

#define MFMA16(a,b,c) __builtin_amdgcn_mfma_f32_16x16x32_bf16((a),(b),(c),0,0,0)
#define GLD16(g,l) __builtin_amdgcn_global_load_lds( \
    (const __attribute__((address_space(1))) void*)(g), \
    (__attribute__((address_space(3))) void*)(l), 16, 0, 0)

// ---------------------------------------------------------------------------
// Weight transpose + f32->bf16:  in [z][K][N] f32  ->  out [z][N][K] bf16
// ---------------------------------------------------------------------------
__global__ __launch_bounds__(256) void transpose_w(
    const float* __restrict__ in, __hip_bfloat16* __restrict__ out, int K, int N)
{
    __shared__ float t[32][33];
    const int z = blockIdx.z;
    const float* src = in + (size_t)z * K * N;
    __hip_bfloat16* dst = out + (size_t)z * N * K;
    const int n0 = blockIdx.x * 32, k0 = blockIdx.y * 32;
    const int tx = threadIdx.x, ty = threadIdx.y;   // (32,8)
#pragma unroll
    for (int r = ty; r < 32; r += 8)
        t[r][tx] = src[(size_t)(k0 + r) * N + n0 + tx];
    __syncthreads();
#pragma unroll
    for (int r = ty; r < 32; r += 8)
        dst[(size_t)(n0 + r) * K + k0 + tx] = __float2bfloat16(t[tx][r]);
}

// ---------------------------------------------------------------------------
// f32 copy (x -> workspace residual stream)
// ---------------------------------------------------------------------------
__global__ void copy_f32x4(const float4* __restrict__ in, float4* __restrict__ out, int n)
{
    int i = blockIdx.x * blockDim.x + threadIdx.x;
    if (i < n) out[i] = in[i];
}

// ---------------------------------------------------------------------------
// LayerNorm: one wave per row (D=512 -> 8 f32/lane). OUT = bf16 or f32.
// ---------------------------------------------------------------------------
template <typename OUT>
__global__ __launch_bounds__(256) void ln_kernel(
    const float* __restrict__ x, const float* __restrict__ g,
    const float* __restrict__ be, OUT* __restrict__ out)
{
    const int row  = blockIdx.x * 4 + (threadIdx.x >> 6);
    const int lane = threadIdx.x & 63;
    const int c0   = lane * 8;
    const float* xr = x + (size_t)row * D_ + c0;
    float4 a = *(const float4*)xr;
    float4 c = *(const float4*)(xr + 4);
    float v[8] = {a.x, a.y, a.z, a.w, c.x, c.y, c.z, c.w};

    float s = 0.f;
#pragma unroll
    for (int j = 0; j < 8; ++j) s += v[j];
#pragma unroll
    for (int o = 1; o < 64; o <<= 1) s += __shfl_xor(s, o, 64);
    const float mu = s * (1.0f / D_);

    float s2 = 0.f;
#pragma unroll
    for (int j = 0; j < 8; ++j) { float d = v[j] - mu; s2 += d * d; }
#pragma unroll
    for (int o = 1; o < 64; o <<= 1) s2 += __shfl_xor(s2, o, 64);
    const float rs = rsqrtf(s2 * (1.0f / D_) + 1e-5f);

    float4 g0 = *(const float4*)(g + c0);
    float4 g1 = *(const float4*)(g + c0 + 4);
    float4 b0 = *(const float4*)(be + c0);
    float4 b1 = *(const float4*)(be + c0 + 4);
    float gg[8] = {g0.x, g0.y, g0.z, g0.w, g1.x, g1.y, g1.z, g1.w};
    float bb[8] = {b0.x, b0.y, b0.z, b0.w, b1.x, b1.y, b1.z, b1.w};

    if constexpr (sizeof(OUT) == 2) {
        bf16x8 o8;
#pragma unroll
        for (int j = 0; j < 8; ++j)
            o8[j] = (__bf16)((v[j] - mu) * rs * gg[j] + bb[j]);
        *(bf16x8*)((__hip_bfloat16*)out + (size_t)row * D_ + c0) = o8;
    } else {
        float* op = (float*)out + (size_t)row * D_ + c0;
        float4 r0, r1;
        r0.x = (v[0]-mu)*rs*gg[0]+bb[0]; r0.y = (v[1]-mu)*rs*gg[1]+bb[1];
        r0.z = (v[2]-mu)*rs*gg[2]+bb[2]; r0.w = (v[3]-mu)*rs*gg[3]+bb[3];
        r1.x = (v[4]-mu)*rs*gg[4]+bb[4]; r1.y = (v[5]-mu)*rs*gg[5]+bb[5];
        r1.z = (v[6]-mu)*rs*gg[6]+bb[6]; r1.w = (v[7]-mu)*rs*gg[7]+bb[7];
        *(float4*)op = r0; *(float4*)(op + 4) = r1;
    }
}

// ---------------------------------------------------------------------------
// GEMM: C[M][N] = A[M][K] @ BT[N][K]^T + bias[N], bf16 inputs, f32 accum.
// 128x128 tile, BK=32, 4 waves (each 64x64 = 4x4 16x16 frags), m97 structure.
// EPI: 0 = bf16 store; 1 = f32 residual add (Cout==Res); 2 = exact GELU->bf16;
//      3 = transposed bf16 store into VT[b][n][l]  (m = b*512 + l)
// ---------------------------------------------------------------------------
template <int EPI>
__global__ __launch_bounds__(256) void gemm_bt(
    const __hip_bfloat16* __restrict__ A,
    const __hip_bfloat16* __restrict__ BT,
    const float* __restrict__ bias,
    void* Cout, const float* Res,
    int Ndim, int K)
{
    __shared__ __align__(16) __hip_bfloat16 As[128 * 32];
    __shared__ __align__(16) __hip_bfloat16 Bs[128 * 32];

    const int t  = threadIdx.x;
    const int w  = t >> 6;
    const int l  = t & 63;
    const int lq = l & 15, lg = l >> 4;
    const int m0 = blockIdx.y * 128, n0 = blockIdx.x * 128;
    const int wr = (w >> 1) * 64, wc = (w & 1) * 64;

    f32x4 acc[4][4] = {};

    const int srow = t >> 2;          // 0..63
    const int scol = (t & 3) * 8;     // 0,8,16,24
    const __hip_bfloat16* ga = A  + (size_t)(m0 + srow) * K + scol;
    const __hip_bfloat16* gb = BT + (size_t)(n0 + srow) * K + scol;
    char* lA = (char*)As + w * 1024;  // wave-uniform LDS base (+ lane*16 by HW)
    char* lB = (char*)Bs + w * 1024;
    const __hip_bfloat16* ra = As + (wr + lq) * 32 + lg * 8;
    const __hip_bfloat16* rb = Bs + (wc + lq) * 32 + lg * 8;

    for (int k0 = 0; k0 < K; k0 += 32) {
        GLD16(ga, lA);
        GLD16(ga + (size_t)64 * K, lA + 4096);
        GLD16(gb, lB);
        GLD16(gb + (size_t)64 * K, lB + 4096);
        ga += 32; gb += 32;
        __syncthreads();   // drains vmcnt (global_load_lds) + barrier

        bf16x8 af[4], bfg[4];
#pragma unroll
        for (int i = 0; i < 4; ++i) af[i]  = *(const bf16x8*)(ra + i * 16 * 32);
#pragma unroll
        for (int j = 0; j < 4; ++j) bfg[j] = *(const bf16x8*)(rb + j * 16 * 32);
#pragma unroll
        for (int i = 0; i < 4; ++i)
#pragma unroll
            for (int j = 0; j < 4; ++j)
                acc[i][j] = MFMA16(af[i], bfg[j], acc[i][j]);
        __syncthreads();   // before next stage overwrites LDS
    }

    float bcol[4];
#pragma unroll
    for (int j = 0; j < 4; ++j) bcol[j] = bias[n0 + wc + j * 16 + lq];

#pragma unroll
    for (int i = 0; i < 4; ++i) {
#pragma unroll
        for (int j = 0; j < 4; ++j) {
            const int n = n0 + wc + j * 16 + lq;
#pragma unroll
            for (int r = 0; r < 4; ++r) {
                const int m = m0 + wr + i * 16 + lg * 4 + r;
                float v = acc[i][j][r] + bcol[j];
                if constexpr (EPI == 0) {
                    ((__hip_bfloat16*)Cout)[(size_t)m * Ndim + n] = __float2bfloat16(v);
                } else if constexpr (EPI == 1) {
                    float* Co = (float*)Cout;
                    const size_t idx = (size_t)m * Ndim + n;
                    Co[idx] = Res[idx] + v;
                } else if constexpr (EPI == 2) {
                    float gl = 0.5f * v * (1.0f + erff(v * 0.70710678118654752f));
                    ((__hip_bfloat16*)Cout)[(size_t)m * Ndim + n] = __float2bfloat16(gl);
                } else {  // EPI == 3: VT[b][n][l], m = b*512 + l
                    ((__hip_bfloat16*)Cout)[((size_t)(m >> 9) * D_ + n) * L_ + (m & 511)]
                        = __float2bfloat16(v);
                }
            }
        }
    }
}

// ---------------------------------------------------------------------------
// Flash attention, 1 wave per (b, h, 16-row q-tile). Swapped QK^T (mfma(K,Q))
// so each lane owns one q-row; kv tiles of 32.
//   Q,K: bf16 [b][l][h][hd] (= [m][n] GEMM layout). VT: bf16 [b][h*64+hd][l].
//   Out: bf16 [m][n] for the Wo GEMM.
// ---------------------------------------------------------------------------
__global__ __launch_bounds__(64) void attn_kernel(
    const __hip_bfloat16* __restrict__ Q, const __hip_bfloat16* __restrict__ K,
    const __hip_bfloat16* __restrict__ VT, __hip_bfloat16* __restrict__ Out,
    const int* __restrict__ case_ids, const int* __restrict__ amask,
    const float* __restrict__ case_bias, const float* __restrict__ verb_bias,
    int layer)
{
    __shared__ int   s_cj[L_];
    __shared__ float s_add[L_];
    __shared__ __align__(16) __bf16 s_p[16 * 32];

    const int bid = blockIdx.x;
    const int qt = bid & 31, hh = (bid >> 5) & 7, b = bid >> 8;
    const int lane = threadIdx.x, lq = lane & 15, lg = lane >> 4;

    const float vb = verb_bias[layer * H_ + hh];
    for (int j = lane; j < L_; j += 64) {
        int cid = case_ids[b * L_ + j];
        s_cj[j]  = cid;
        s_add[j] = (cid == 8 ? vb : 0.f) - 10000.f * (1.f - (float)amask[b * L_ + j]);
    }
    __syncthreads();

    const int qrow = qt * 16 + lq;
    const int ci_q = s_cj[qrow];
    const float* cbrow = case_bias + (((size_t)layer * H_ + hh) * C_ + ci_q) * C_;

    const __hip_bfloat16* qp = Q + ((size_t)b * L_ + qrow) * D_ + hh * HD_ + lg * 8;
    const bf16x8 qf0 = *(const bf16x8*)qp;
    const bf16x8 qf1 = *(const bf16x8*)(qp + 32);

    float m_run = -1e30f, l_run = 0.f;
    f32x4 o[4] = {};

    const int ntiles = qt / 2 + 1;
    for (int kt = 0; kt < ntiles; ++kt) {
        const int kv0 = kt * 32;
        const __hip_bfloat16* kp = K + ((size_t)b * L_ + kv0 + lq) * D_ + hh * HD_ + lg * 8;
        bf16x8 ka0 = *(const bf16x8*)kp;
        bf16x8 ka1 = *(const bf16x8*)(kp + 32);
        bf16x8 kb0 = *(const bf16x8*)(kp + (size_t)16 * D_);
        bf16x8 kb1 = *(const bf16x8*)(kp + (size_t)16 * D_ + 32);

        f32x4 s0 = {}, s1 = {};
        s0 = MFMA16(ka0, qf0, s0); s0 = MFMA16(ka1, qf1, s0);
        s1 = MFMA16(kb0, qf0, s1); s1 = MFMA16(kb1, qf1, s1);
        // lane holds S[q=lq][kv = kv0 + lg*4 + r]  (s1: +16)

        float xs[8];
#pragma unroll
        for (int r = 0; r < 4; ++r) {
            int kva = kv0 + lg * 4 + r;
            int kvb = kva + 16;
            xs[r]     = s0[r] * 0.125f + cbrow[s_cj[kva]] + s_add[kva]
                        + (kva > qrow ? -10000.f : 0.f);
            xs[4 + r] = s1[r] * 0.125f + cbrow[s_cj[kvb]] + s_add[kvb]
                        + (kvb > qrow ? -10000.f : 0.f);
        }

        float pmax = xs[0];
#pragma unroll
        for (int j = 1; j < 8; ++j) pmax = fmaxf(pmax, xs[j]);
        pmax = fmaxf(pmax, __shfl_xor(pmax, 16, 64));
        pmax = fmaxf(pmax, __shfl_xor(pmax, 32, 64));

        const float mnew = fmaxf(m_run, pmax);
        const float corr = __expf(m_run - mnew);
        float p[8], ps = 0.f;
#pragma unroll
        for (int j = 0; j < 8; ++j) { p[j] = __expf(xs[j] - mnew); ps += p[j]; }
        ps += __shfl_xor(ps, 16, 64);
        ps += __shfl_xor(ps, 32, 64);
        l_run = l_run * corr + ps;
        m_run = mnew;

        float cr[4];
#pragma unroll
        for (int r = 0; r < 4; ++r) cr[r] = __shfl(corr, lg * 4 + r, 64);
#pragma unroll
        for (int nt = 0; nt < 4; ++nt)
#pragma unroll
            for (int r = 0; r < 4; ++r) o[nt][r] *= cr[r];

        // stage P (bf16) into LDS in A-fragment layout [q=16][kv=32]
        bf16x4 pa, pb_;
#pragma unroll
        for (int r = 0; r < 4; ++r) { pa[r] = (__bf16)p[r]; pb_[r] = (__bf16)p[4 + r]; }
        *(bf16x4*)(s_p + lq * 32 + lg * 4)      = pa;
        *(bf16x4*)(s_p + lq * 32 + 16 + lg * 4) = pb_;
        __syncthreads();

        const bf16x8 pf = *(const bf16x8*)(s_p + lq * 32 + lg * 8);
#pragma unroll
        for (int nt = 0; nt < 4; ++nt) {
            const bf16x8 vf = *(const bf16x8*)(VT
                + ((size_t)b * D_ + hh * HD_ + nt * 16 + lq) * L_ + kv0 + lg * 8);
            o[nt] = MFMA16(pf, vf, o[nt]);
        }
        __syncthreads();
    }

    const float inv = 1.f / l_run;
    float ir[4];
#pragma unroll
    for (int r = 0; r < 4; ++r) ir[r] = __shfl(inv, lg * 4 + r, 64);
#pragma unroll
    for (int nt = 0; nt < 4; ++nt)
#pragma unroll
        for (int r = 0; r < 4; ++r)
            Out[((size_t)b * L_ + qt * 16 + lg * 4 + r) * D_ + hh * HD_ + nt * 16 + lq]
                = __float2bfloat16(o[nt][r] * ir[r]);
}

// ---------------------------------------------------------------------------
extern "C" void kernel_launch(void* const* d_in, const int* in_sizes, int n_in,
                              void* d_out, int out_size, void* d_ws, size_t ws_size,
                              hipStream_t stream)
{
    const float* x_in  = (const float*)d_in[0];
    const int*   cids  = (const int*)  d_in[1];
    const int*   amask = (const int*)  d_in[2];
    const float* Wq = (const float*)d_in[3];
    const float* bq = (const float*)d_in[4];
    const float* Wk = (const float*)d_in[5];
    const float* bk = (const float*)d_in[6];
    const float* Wv = (const float*)d_in[7];
    const float* bv = (const float*)d_in[8];
    const float* Wo = (const float*)d_in[9];
    const float* bo = (const float*)d_in[10];
    const float* ln1g = (const float*)d_in[11];
    const float* ln1b = (const float*)d_in[12];
    const float* ln2g = (const float*)d_in[13];
    const float* ln2b = (const float*)d_in[14];
    const float* W1 = (const float*)d_in[15];
    const float* b1 = (const float*)d_in[16];
    const float* W2 = (const float*)d_in[17];
    const float* b2 = (const float*)d_in[18];
    const float* cbias = (const float*)d_in[19];
    const float* vbias = (const float*)d_in[20];
    const float* fng = (const float*)d_in[21];
    const float* fnb = (const float*)d_in[22];

    char* w = (char*)d_ws;
    float* x_ws = (float*)w;                 w += (size_t)MTOK * D_ * 4;
    __hip_bfloat16* hbuf = (__hip_bfloat16*)w; w += (size_t)MTOK * D_ * 2;
    __hip_bfloat16* qbuf = (__hip_bfloat16*)w; w += (size_t)MTOK * D_ * 2;
    __hip_bfloat16* kbuf = (__hip_bfloat16*)w; w += (size_t)MTOK * D_ * 2;
    __hip_bfloat16* vtb  = (__hip_bfloat16*)w; w += (size_t)MTOK * D_ * 2;
    __hip_bfloat16* ffb  = (__hip_bfloat16*)w; w += (size_t)MTOK * F_ * 2;
    __hip_bfloat16* WqT  = (__hip_bfloat16*)w; w += (size_t)NL_ * D_ * D_ * 2;
    __hip_bfloat16* WkT  = (__hip_bfloat16*)w; w += (size_t)NL_ * D_ * D_ * 2;
    __hip_bfloat16* WvT  = (__hip_bfloat16*)w; w += (size_t)NL_ * D_ * D_ * 2;
    __hip_bfloat16* WoT  = (__hip_bfloat16*)w; w += (size_t)NL_ * D_ * D_ * 2;
    __hip_bfloat16* W1T  = (__hip_bfloat16*)w; w += (size_t)NL_ * D_ * F_ * 2;
    __hip_bfloat16* W2T  = (__hip_bfloat16*)w; w += (size_t)NL_ * D_ * F_ * 2;

    const dim3 tb(32, 8);
    transpose_w<<<dim3(D_/32, D_/32, NL_), tb, 0, stream>>>(Wq, WqT, D_, D_);
    transpose_w<<<dim3(D_/32, D_/32, NL_), tb, 0, stream>>>(Wk, WkT, D_, D_);
    transpose_w<<<dim3(D_/32, D_/32, NL_), tb, 0, stream>>>(Wv, WvT, D_, D_);
    transpose_w<<<dim3(D_/32, D_/32, NL_), tb, 0, stream>>>(Wo, WoT, D_, D_);
    transpose_w<<<dim3(F_/32, D_/32, NL_), tb, 0, stream>>>(W1, W1T, D_, F_);
    transpose_w<<<dim3(D_/32, F_/32, NL_), tb, 0, stream>>>(W2, W2T, F_, D_);

    copy_f32x4<<<8192, 256, 0, stream>>>((const float4*)x_in, (float4*)x_ws,
                                         MTOK * D_ / 4);

    const dim3 g512(D_/128, MTOK/128);   // (4,128)
    const dim3 g2048(F_/128, MTOK/128);  // (16,128)

    for (int i = 0; i < NL_; ++i) {
        ln_kernel<__hip_bfloat16><<<MTOK/4, 256, 0, stream>>>(
            x_ws, ln1g + i * D_, ln1b + i * D_, hbuf);

        gemm_bt<0><<<g512, 256, 0, stream>>>(hbuf, WqT + (size_t)i*D_*D_,
            bq + i*D_, qbuf, nullptr, D_, D_);
        gemm_bt<0><<<g512, 256, 0, stream>>>(hbuf, WkT + (size_t)i*D_*D_,
            bk + i*D_, kbuf, nullptr, D_, D_);
        gemm_bt<3><<<g512, 256, 0, stream>>>(hbuf, WvT + (size_t)i*D_*D_,
            bv + i*D_, vtb, nullptr, D_, D_);

        attn_kernel<<<B_ * H_ * (L_/16), 64, 0, stream>>>(
            qbuf, kbuf, vtb, hbuf, cids, amask, cbias, vbias, i);

        gemm_bt<1><<<g512, 256, 0, stream>>>(hbuf, WoT + (size_t)i*D_*D_,
            bo + i*D_, x_ws, x_ws, D_, D_);

        ln_kernel<__hip_bfloat16><<<MTOK/4, 256, 0, stream>>>(
            x_ws, ln2g + i * D_, ln2b + i * D_, hbuf);

        gemm_bt<2><<<g2048, 256, 0, stream>>>(hbuf, W1T + (size_t)i*D_*F_,
            b1 + i*F_, ffb, nullptr, F_, D_);
        gemm_bt<1><<<g512, 256, 0, stream>>>(ffb, W2T + (size_t)i*D_*F_,
            b2 + i*D_, x_ws, x_ws, D_, F_);
    }

    ln_kernel<float><<<MTOK/4, 256, 0, stream>>>(x_ws, fng, fnb, (float*)d_out);
}

// Round 2
// 1749.478 us; speedup vs baseline: 1.4094x; 1.4094x over previous
//
#include <hip/hip_runtime.h>
#include <hip/hip_bf16.h>

// Problem constants
#define B_   32
#define L_   512
#define D_   512
#define H_   8
#define NL_  6
#define F_   2048
#define C_   9
#define HD_  64
#define MTOK 16384   // B_*L_

typedef __bf16 bf16x8 __attribute__((ext_vector_type(8)));
typedef __bf16 bf16x4 __attribute__((ext_vector_type(4)));
typedef float  f32x4  __attribute__((ext_vector_type(4)));

#define MFMA16(a,b,c) __builtin_amdgcn_mfma_f32_16x16x32_bf16((a),(b),(c),0,0,0)
#define GLD16(g,l) __builtin_amdgcn_global_load_lds( \
    (const __attribute__((address_space(1))) void*)(g), \
    (__attribute__((address_space(3))) void*)(l), 16, 0, 0)

// ---------------------------------------------------------------------------
// Weight transpose + f32->bf16:  in [z][K][N] f32  ->  out [z][N][K] bf16
// ---------------------------------------------------------------------------
__global__ __launch_bounds__(256) void transpose_w(
    const float* __restrict__ in, __hip_bfloat16* __restrict__ out, int K, int N)
{
    __shared__ float t[32][33];
    const int z = blockIdx.z;
    const float* src = in + (size_t)z * K * N;
    __hip_bfloat16* dst = out + (size_t)z * N * K;
    const int n0 = blockIdx.x * 32, k0 = blockIdx.y * 32;
    const int tx = threadIdx.x, ty = threadIdx.y;   // (32,8)
#pragma unroll
    for (int r = ty; r < 32; r += 8)
        t[r][tx] = src[(size_t)(k0 + r) * N + n0 + tx];
    __syncthreads();
#pragma unroll
    for (int r = ty; r < 32; r += 8)
        dst[(size_t)(n0 + r) * K + k0 + tx] = __float2bfloat16(t[tx][r]);
}

// ---------------------------------------------------------------------------
__global__ void copy_f32x4(const float4* __restrict__ in, float4* __restrict__ out, int n)
{
    int i = blockIdx.x * blockDim.x + threadIdx.x;
    if (i < n) out[i] = in[i];
}

// ---------------------------------------------------------------------------
// LayerNorm: one wave per row (D=512 -> 8 f32/lane). OUT = bf16 or f32.
// ---------------------------------------------------------------------------
template <typename OUT>
__global__ __launch_bounds__(256) void ln_kernel(
    const float* __restrict__ x, const float* __restrict__ g,
    const float* __restrict__ be, OUT* __restrict__ out)
{
    const int row  = blockIdx.x * 4 + (threadIdx.x >> 6);
    const int lane = threadIdx.x & 63;
    const int c0   = lane * 8;
    const float* xr = x + (size_t)row * D_ + c0;
    float4 a = *(const float4*)xr;
    float4 c = *(const float4*)(xr + 4);
    float v[8] = {a.x, a.y, a.z, a.w, c.x, c.y, c.z, c.w};

    float s = 0.f;
#pragma unroll
    for (int j = 0; j < 8; ++j) s += v[j];
#pragma unroll
    for (int o = 1; o < 64; o <<= 1) s += __shfl_xor(s, o, 64);
    const float mu = s * (1.0f / D_);

    float s2 = 0.f;
#pragma unroll
    for (int j = 0; j < 8; ++j) { float d = v[j] - mu; s2 += d * d; }
#pragma unroll
    for (int o = 1; o < 64; o <<= 1) s2 += __shfl_xor(s2, o, 64);
    const float rs = rsqrtf(s2 * (1.0f / D_) + 1e-5f);

    float4 g0 = *(const float4*)(g + c0);
    float4 g1 = *(const float4*)(g + c0 + 4);
    float4 b0 = *(const float4*)(be + c0);
    float4 b1 = *(const float4*)(be + c0 + 4);
    float gg[8] = {g0.x, g0.y, g0.z, g0.w, g1.x, g1.y, g1.z, g1.w};
    float bb[8] = {b0.x, b0.y, b0.z, b0.w, b1.x, b1.y, b1.z, b1.w};

    if constexpr (sizeof(OUT) == 2) {
        bf16x8 o8;
#pragma unroll
        for (int j = 0; j < 8; ++j)
            o8[j] = (__bf16)((v[j] - mu) * rs * gg[j] + bb[j]);
        *(bf16x8*)((__hip_bfloat16*)out + (size_t)row * D_ + c0) = o8;
    } else {
        float* op = (float*)out + (size_t)row * D_ + c0;
        float4 r0, r1;
        r0.x = (v[0]-mu)*rs*gg[0]+bb[0]; r0.y = (v[1]-mu)*rs*gg[1]+bb[1];
        r0.z = (v[2]-mu)*rs*gg[2]+bb[2]; r0.w = (v[3]-mu)*rs*gg[3]+bb[3];
        r1.x = (v[4]-mu)*rs*gg[4]+bb[4]; r1.y = (v[5]-mu)*rs*gg[5]+bb[5];
        r1.z = (v[6]-mu)*rs*gg[6]+bb[6]; r1.w = (v[7]-mu)*rs*gg[7]+bb[7];
        *(float4*)op = r0; *(float4*)(op + 4) = r1;
    }
}

// ---------------------------------------------------------------------------
// GEMM: C[M][N] = A[M][K] @ BT[N][K]^T + bias[N], bf16 in, f32 accum.
// 128x128 tile, BK=32, 4 waves, m97 structure + bijective XCD swizzle (m204).
// EPI: 0=bf16 store; 1=f32 residual add; 2=exact GELU->bf16; 3=VT[b][n][l]
// ---------------------------------------------------------------------------
template <int EPI>
__global__ __launch_bounds__(256) void gemm_bt(
    const __hip_bfloat16* __restrict__ A,
    const __hip_bfloat16* __restrict__ BT,
    const float* __restrict__ bias,
    void* Cout, const float* Res,
    int Ndim, int K)
{
    __shared__ __align__(16) __hip_bfloat16 As[128 * 32];
    __shared__ __align__(16) __hip_bfloat16 Bs[128 * 32];

    const int t  = threadIdx.x;
    const int w  = t >> 6;
    const int l  = t & 63;
    const int lq = l & 15, lg = l >> 4;

    // bijective XCD swizzle (nwg % 8 == 0 for all launches here)
    const int nwg = gridDim.x * gridDim.y;
    int flat = blockIdx.y * gridDim.x + blockIdx.x;
    {
        const int qq = nwg >> 3, rr = nwg & 7;
        const int xcd = flat & 7, off = flat >> 3;
        flat = (xcd < rr ? xcd * (qq + 1) : rr * (qq + 1) + (xcd - rr) * qq) + off;
    }
    const int bx = flat % gridDim.x, by = flat / gridDim.x;
    const int m0 = by * 128, n0 = bx * 128;
    const int wr = (w >> 1) * 64, wc = (w & 1) * 64;

    f32x4 acc[4][4] = {};

    const int srow = t >> 2;
    const int scol = (t & 3) * 8;
    const __hip_bfloat16* ga = A  + (size_t)(m0 + srow) * K + scol;
    const __hip_bfloat16* gb = BT + (size_t)(n0 + srow) * K + scol;
    char* lA = (char*)As + w * 1024;
    char* lB = (char*)Bs + w * 1024;
    const __hip_bfloat16* ra = As + (wr + lq) * 32 + lg * 8;
    const __hip_bfloat16* rb = Bs + (wc + lq) * 32 + lg * 8;

    for (int k0 = 0; k0 < K; k0 += 32) {
        GLD16(ga, lA);
        GLD16(ga + (size_t)64 * K, lA + 4096);
        GLD16(gb, lB);
        GLD16(gb + (size_t)64 * K, lB + 4096);
        ga += 32; gb += 32;
        __syncthreads();

        bf16x8 af[4], bfg[4];
#pragma unroll
        for (int i = 0; i < 4; ++i) af[i]  = *(const bf16x8*)(ra + i * 16 * 32);
#pragma unroll
        for (int j = 0; j < 4; ++j) bfg[j] = *(const bf16x8*)(rb + j * 16 * 32);
#pragma unroll
        for (int i = 0; i < 4; ++i)
#pragma unroll
            for (int j = 0; j < 4; ++j)
                acc[i][j] = MFMA16(af[i], bfg[j], acc[i][j]);
        __syncthreads();
    }

    float bcol[4];
#pragma unroll
    for (int j = 0; j < 4; ++j) bcol[j] = bias[n0 + wc + j * 16 + lq];

#pragma unroll
    for (int i = 0; i < 4; ++i) {
#pragma unroll
        for (int j = 0; j < 4; ++j) {
            const int n = n0 + wc + j * 16 + lq;
#pragma unroll
            for (int r = 0; r < 4; ++r) {
                const int m = m0 + wr + i * 16 + lg * 4 + r;
                float v = acc[i][j][r] + bcol[j];
                if constexpr (EPI == 0) {
                    ((__hip_bfloat16*)Cout)[(size_t)m * Ndim + n] = __float2bfloat16(v);
                } else if constexpr (EPI == 1) {
                    float* Co = (float*)Cout;
                    const size_t idx = (size_t)m * Ndim + n;
                    Co[idx] = Res[idx] + v;
                } else if constexpr (EPI == 2) {
                    float gl = 0.5f * v * (1.0f + erff(v * 0.70710678118654752f));
                    ((__hip_bfloat16*)Cout)[(size_t)m * Ndim + n] = __float2bfloat16(gl);
                } else {  // EPI == 3: VT[b][n][l], m = b*512 + l
                    ((__hip_bfloat16*)Cout)[((size_t)(m >> 9) * D_ + n) * L_ + (m & 511)]
                        = __float2bfloat16(v);
                }
            }
        }
    }
}

// ---------------------------------------------------------------------------
// Flash attention v2: 4 waves/block, 64 q-rows/block, KV tiles of 64,
// K/V double-buffered in LDS via global_load_lds with pre-swizzled source
// (XOR st-16 swizzle -> conflict-free ds_read_b128). Swapped QK^T (mfma(K,Q)).
// Grid: (b*H+h, qc) so all qc-blocks of one (b,h) share an XCD L2.
//   Q,K: bf16 [b][l][D] head slice; VT: bf16 [b][d][l]; Out: bf16 [b][l][D].
// ---------------------------------------------------------------------------
__global__ __launch_bounds__(256) void attn_kernel(
    const __hip_bfloat16* __restrict__ Q, const __hip_bfloat16* __restrict__ K,
    const __hip_bfloat16* __restrict__ VT, __hip_bfloat16* __restrict__ Out,
    const int* __restrict__ case_ids, const int* __restrict__ amask,
    const float* __restrict__ case_bias, const float* __restrict__ verb_bias,
    int layer)
{
    __shared__ __align__(16) __bf16 Ks[2][64 * 64];   // [kv][hd], row-swizzled
    __shared__ __align__(16) __bf16 Vs[2][64 * 64];   // [hd][kv], row-swizzled
    __shared__ __align__(16) __bf16 Pl[4][16 * 64];   // per-wave P, swizzled
    __shared__ __bf16 Bia[9][520];                    // bias[ci][kv], padded

    const int bh = blockIdx.x;
    const int b = bh >> 3, hh = bh & 7;
    const int qc = blockIdx.y;                        // 0..7
    const int t = threadIdx.x;
    const int w = t >> 6, lane = t & 63;
    const int lq = lane & 15, lg = lane >> 4;
    const int swz = lq & 7;

    // staging geometry: wave w stages rows [w*16, w*16+16) of each 64-row tile
    const int rA = w * 16 + (lane >> 3);
    const int swsrc = ((lane & 7) ^ (lane >> 3)) << 4;   // pre-swizzled source slot
    const __hip_bfloat16* kg0 = K  + ((size_t)b * L_ + rA) * D_ + hh * HD_;
    const __hip_bfloat16* vg0 = VT + ((size_t)b * D_ + hh * HD_ + rA) * L_;

    auto stage = [&](int buf, int kv0) {
        const char* gk = (const char*)(kg0 + (size_t)kv0 * D_) + swsrc;
        GLD16(gk,                    (char*)Ks[buf] + w * 2048);
        GLD16(gk + (size_t)8 * D_ * 2, (char*)Ks[buf] + w * 2048 + 1024);
        const char* gv = (const char*)(vg0 + kv0) + swsrc;
        GLD16(gv,                    (char*)Vs[buf] + w * 2048);
        GLD16(gv + (size_t)8 * L_ * 2, (char*)Vs[buf] + w * 2048 + 1024);
    };

    stage(0, 0);

    // bias table: Bia[ci][kv] = case_bias[l][h][ci][cj(kv)] + verb + pad
    const float vb = verb_bias[layer * H_ + hh];
    const float* cb = case_bias + ((size_t)layer * H_ + hh) * (C_ * C_);
    for (int idx = t; idx < 9 * 512; idx += 256) {
        const int ci = idx >> 9, kv = idx & 511;
        const int cj = case_ids[b * L_ + kv];
        Bia[ci][kv] = (__bf16)(cb[ci * C_ + cj] + (cj == 8 ? vb : 0.f)
                               - 10000.f * (1.f - (float)amask[b * L_ + kv]));
    }
    __syncthreads();

    const int qloc = w * 16 + lq;
    const int qrow = qc * 64 + qloc;
    const int ci_q = case_ids[b * L_ + qrow];
    const __hip_bfloat16* qp = Q + ((size_t)b * L_ + qrow) * D_ + hh * HD_;
    const bf16x8 qf0 = *(const bf16x8*)(qp + lg * 8);
    const bf16x8 qf1 = *(const bf16x8*)(qp + 32 + lg * 8);

    float m_run = -1e30f, l_run = 0.f;
    f32x4 o[4] = {};
    const int ntiles = qc + 1;
    int cur = 0;

    for (int kt = 0; kt < ntiles; ++kt) {
        if (kt + 1 < ntiles) stage(cur ^ 1, (kt + 1) * 64);

        const char* kb  = (const char*)Ks[cur];
        const char* vb2 = (const char*)Vs[cur];

        // QK^T: S[kv 64][q 16] per wave, lane owns q-col lq, regs span kv
        f32x4 s[4] = {};
        __builtin_amdgcn_s_setprio(1);
#pragma unroll
        for (int c = 0; c < 4; ++c) {
            const bf16x8 ka = *(const bf16x8*)(kb + (16 * c + lq) * 128 + ((lg ^ swz) << 4));
            s[c] = MFMA16(ka, qf0, s[c]);
            const bf16x8 kc = *(const bf16x8*)(kb + (16 * c + lq) * 128 + (((4 + lg) ^ swz) << 4));
            s[c] = MFMA16(kc, qf1, s[c]);
        }
        __builtin_amdgcn_s_setprio(0);

        const __bf16* brow = &Bia[ci_q][kt * 64];
        const bool dtile = (kt == qc);
        float xs[16];
#pragma unroll
        for (int c = 0; c < 4; ++c) {
            const bf16x4 bb = *(const bf16x4*)(brow + 16 * c + lg * 4);
#pragma unroll
            for (int r = 0; r < 4; ++r) {
                const int kvl = 16 * c + lg * 4 + r;
                float v = s[c][r] * 0.125f + (float)bb[r];
                xs[4 * c + r] = (dtile && (kvl > qloc)) ? -1e9f : v;
            }
        }

        float a0 = fmaxf(fmaxf(xs[0], xs[1]),  fmaxf(xs[2], xs[3]));
        float a1 = fmaxf(fmaxf(xs[4], xs[5]),  fmaxf(xs[6], xs[7]));
        float a2 = fmaxf(fmaxf(xs[8], xs[9]),  fmaxf(xs[10], xs[11]));
        float a3 = fmaxf(fmaxf(xs[12], xs[13]), fmaxf(xs[14], xs[15]));
        float pmax = fmaxf(fmaxf(a0, a1), fmaxf(a2, a3));
        pmax = fmaxf(pmax, __shfl_xor(pmax, 16, 64));
        pmax = fmaxf(pmax, __shfl_xor(pmax, 32, 64));

        const float mnew = fmaxf(m_run, pmax);
        const float corr = __expf(m_run - mnew);
        float p[16], ps0 = 0.f, ps1 = 0.f;
#pragma unroll
        for (int j = 0; j < 16; j += 2) {
            p[j]     = __expf(xs[j] - mnew);     ps0 += p[j];
            p[j + 1] = __expf(xs[j + 1] - mnew); ps1 += p[j + 1];
        }
        float ps = ps0 + ps1;
        ps += __shfl_xor(ps, 16, 64);
        ps += __shfl_xor(ps, 32, 64);
        l_run = l_run * corr + ps;
        m_run = mnew;

        float cr[4];
#pragma unroll
        for (int r = 0; r < 4; ++r) cr[r] = __shfl(corr, lg * 4 + r, 64);
#pragma unroll
        for (int nt = 0; nt < 4; ++nt)
#pragma unroll
            for (int r = 0; r < 4; ++r) o[nt][r] *= cr[r];

        // stage P into per-wave LDS (same swizzle family)
        char* pw = (char*)Pl[w];
#pragma unroll
        for (int c = 0; c < 4; ++c) {
            bf16x4 pv;
#pragma unroll
            for (int r = 0; r < 4; ++r) pv[r] = (__bf16)p[4 * c + r];
            const int slot = (2 * c + (lg >> 1)) ^ swz;
            *(bf16x4*)(pw + lq * 128 + (slot << 4) + ((lg & 1) << 3)) = pv;
        }

        __builtin_amdgcn_s_setprio(1);
#pragma unroll
        for (int hf = 0; hf < 2; ++hf) {
            const bf16x8 pf = *(const bf16x8*)(pw + lq * 128 + (((hf * 4 + lg) ^ swz) << 4));
#pragma unroll
            for (int nt = 0; nt < 4; ++nt) {
                const bf16x8 vf = *(const bf16x8*)(vb2 + (nt * 16 + lq) * 128
                                                   + (((hf * 4 + lg) ^ swz) << 4));
                o[nt] = MFMA16(pf, vf, o[nt]);
            }
        }
        __builtin_amdgcn_s_setprio(0);

        __syncthreads();
        cur ^= 1;
    }

    const float inv = 1.f / l_run;
    float ir[4];
#pragma unroll
    for (int r = 0; r < 4; ++r) ir[r] = __shfl(inv, lg * 4 + r, 64);
    __hip_bfloat16* op = Out + ((size_t)b * L_ + qc * 64 + w * 16) * D_ + hh * HD_;
#pragma unroll
    for (int nt = 0; nt < 4; ++nt)
#pragma unroll
        for (int r = 0; r < 4; ++r)
            op[(size_t)(lg * 4 + r) * D_ + nt * 16 + lq] = __float2bfloat16(o[nt][r] * ir[r]);
}

// ---------------------------------------------------------------------------
extern "C" void kernel_launch(void* const* d_in, const int* in_sizes, int n_in,
                              void* d_out, int out_size, void* d_ws, size_t ws_size,
                              hipStream_t stream)
{
    const float* x_in  = (const float*)d_in[0];
    const int*   cids  = (const int*)  d_in[1];
    const int*   amask = (const int*)  d_in[2];
    const float* Wq = (const float*)d_in[3];
    const float* bq = (const float*)d_in[4];
    const float* Wk = (const float*)d_in[5];
    const float* bk = (const float*)d_in[6];
    const float* Wv = (const float*)d_in[7];
    const float* bv = (const float*)d_in[8];
    const float* Wo = (const float*)d_in[9];
    const float* bo = (const float*)d_in[10];
    const float* ln1g = (const float*)d_in[11];
    const float* ln1b = (const float*)d_in[12];
    const float* ln2g = (const float*)d_in[13];
    const float* ln2b = (const float*)d_in[14];
    const float* W1 = (const float*)d_in[15];
    const float* b1 = (const float*)d_in[16];
    const float* W2 = (const float*)d_in[17];
    const float* b2 = (const float*)d_in[18];
    const float* cbias = (const float*)d_in[19];
    const float* vbias = (const float*)d_in[20];
    const float* fng = (const float*)d_in[21];
    const float* fnb = (const float*)d_in[22];

    char* w = (char*)d_ws;
    float* x_ws = (float*)w;                 w += (size_t)MTOK * D_ * 4;
    __hip_bfloat16* hbuf = (__hip_bfloat16*)w; w += (size_t)MTOK * D_ * 2;
    __hip_bfloat16* qbuf = (__hip_bfloat16*)w; w += (size_t)MTOK * D_ * 2;
    __hip_bfloat16* kbuf = (__hip_bfloat16*)w; w += (size_t)MTOK * D_ * 2;
    __hip_bfloat16* vtb  = (__hip_bfloat16*)w; w += (size_t)MTOK * D_ * 2;
    __hip_bfloat16* ffb  = (__hip_bfloat16*)w; w += (size_t)MTOK * F_ * 2;
    __hip_bfloat16* WqT  = (__hip_bfloat16*)w; w += (size_t)NL_ * D_ * D_ * 2;
    __hip_bfloat16* WkT  = (__hip_bfloat16*)w; w += (size_t)NL_ * D_ * D_ * 2;
    __hip_bfloat16* WvT  = (__hip_bfloat16*)w; w += (size_t)NL_ * D_ * D_ * 2;
    __hip_bfloat16* WoT  = (__hip_bfloat16*)w; w += (size_t)NL_ * D_ * D_ * 2;
    __hip_bfloat16* W1T  = (__hip_bfloat16*)w; w += (size_t)NL_ * D_ * F_ * 2;
    __hip_bfloat16* W2T  = (__hip_bfloat16*)w; w += (size_t)NL_ * D_ * F_ * 2;

    const dim3 tb(32, 8);
    transpose_w<<<dim3(D_/32, D_/32, NL_), tb, 0, stream>>>(Wq, WqT, D_, D_);
    transpose_w<<<dim3(D_/32, D_/32, NL_), tb, 0, stream>>>(Wk, WkT, D_, D_);
    transpose_w<<<dim3(D_/32, D_/32, NL_), tb, 0, stream>>>(Wv, WvT, D_, D_);
    transpose_w<<<dim3(D_/32, D_/32, NL_), tb, 0, stream>>>(Wo, WoT, D_, D_);
    transpose_w<<<dim3(F_/32, D_/32, NL_), tb, 0, stream>>>(W1, W1T, D_, F_);
    transpose_w<<<dim3(D_/32, F_/32, NL_), tb, 0, stream>>>(W2, W2T, F_, D_);

    copy_f32x4<<<8192, 256, 0, stream>>>((const float4*)x_in, (float4*)x_ws,
                                         MTOK * D_ / 4);

    const dim3 g512(D_/128, MTOK/128);   // (4,128)
    const dim3 g2048(F_/128, MTOK/128);  // (16,128)

    for (int i = 0; i < NL_; ++i) {
        ln_kernel<__hip_bfloat16><<<MTOK/4, 256, 0, stream>>>(
            x_ws, ln1g + i * D_, ln1b + i * D_, hbuf);

        gemm_bt<0><<<g512, 256, 0, stream>>>(hbuf, WqT + (size_t)i*D_*D_,
            bq + i*D_, qbuf, nullptr, D_, D_);
        gemm_bt<0><<<g512, 256, 0, stream>>>(hbuf, WkT + (size_t)i*D_*D_,
            bk + i*D_, kbuf, nullptr, D_, D_);
        gemm_bt<3><<<g512, 256, 0, stream>>>(hbuf, WvT + (size_t)i*D_*D_,
            bv + i*D_, vtb, nullptr, D_, D_);

        attn_kernel<<<dim3(B_ * H_, L_/64), 256, 0, stream>>>(
            qbuf, kbuf, vtb, hbuf, cids, amask, cbias, vbias, i);

        gemm_bt<1><<<g512, 256, 0, stream>>>(hbuf, WoT + (size_t)i*D_*D_,
            bo + i*D_, x_ws, x_ws, D_, D_);

        ln_kernel<__hip_bfloat16><<<MTOK/4, 256, 0, stream>>>(
            x_ws, ln2g + i * D_, ln2b + i * D_, hbuf);

        gemm_bt<2><<<g2048, 256, 0, stream>>>(hbuf, W1T + (size_t)i*D_*F_,
            b1 + i*F_, ffb, nullptr, F_, D_);
        gemm_bt<1><<<g512, 256, 0, stream>>>(ffb, W2T + (size_t)i*D_*F_,
            b2 + i*D_, x_ws, x_ws, D_, F_);
    }

    ln_kernel<float><<<MTOK/4, 256, 0, stream>>>(x_ws, fng, fnb, (float*)d_out);
}

// Round 3
// 1712.049 us; speedup vs baseline: 1.4402x; 1.0219x over previous
//
#include <hip/hip_runtime.h>
#include <hip/hip_bf16.h>

// Problem constants
#define B_   32
#define L_   512
#define D_   512
#define H_   8
#define NL_  6
#define F_   2048
#define C_   9
#define HD_  64
#define MTOK 16384   // B_*L_

typedef __bf16 bf16x8 __attribute__((ext_vector_type(8)));
typedef __bf16 bf16x4 __attribute__((ext_vector_type(4)));
typedef float  f32x4  __attribute__((ext_vector_type(4)));

#define MFMA16(a,b,c) __builtin_amdgcn_mfma_f32_16x16x32_bf16((a),(b),(c),0,0,0)
#define GLD16(g,l) __builtin_amdgcn_global_load_lds( \
    (const __attribute__((address_space(1))) void*)(g), \
    (__attribute__((address_space(3))) void*)(l), 16, 0, 0)

// ---------------------------------------------------------------------------
// Weight transpose + f32->bf16: in [z][K][N] f32 -> out [z-stride zso][N][K]
// ---------------------------------------------------------------------------
__global__ __launch_bounds__(256) void transpose_w(
    const float* __restrict__ in, __hip_bfloat16* __restrict__ out,
    int K, int N, size_t zso)
{
    __shared__ float t[32][33];
    const int z = blockIdx.z;
    const float* src = in + (size_t)z * K * N;
    __hip_bfloat16* dst = out + (size_t)z * zso;
    const int n0 = blockIdx.x * 32, k0 = blockIdx.y * 32;
    const int tx = threadIdx.x, ty = threadIdx.y;   // (32,8)
#pragma unroll
    for (int r = ty; r < 32; r += 8)
        t[r][tx] = src[(size_t)(k0 + r) * N + n0 + tx];
    __syncthreads();
#pragma unroll
    for (int r = ty; r < 32; r += 8)
        dst[(size_t)(n0 + r) * K + k0 + tx] = __float2bfloat16(t[tx][r]);
}

// ---------------------------------------------------------------------------
__global__ void copy_f32x4(const float4* __restrict__ in, float4* __restrict__ out, int n)
{
    int i = blockIdx.x * blockDim.x + threadIdx.x;
    if (i < n) out[i] = in[i];
}

// ---------------------------------------------------------------------------
// LayerNorm: one wave per row (D=512 -> 8 f32/lane). OUT = bf16 or f32.
// ---------------------------------------------------------------------------
template <typename OUT>
__global__ __launch_bounds__(256) void ln_kernel(
    const float* __restrict__ x, const float* __restrict__ g,
    const float* __restrict__ be, OUT* __restrict__ out)
{
    const int row  = blockIdx.x * 4 + (threadIdx.x >> 6);
    const int lane = threadIdx.x & 63;
    const int c0   = lane * 8;
    const float* xr = x + (size_t)row * D_ + c0;
    float4 a = *(const float4*)xr;
    float4 c = *(const float4*)(xr + 4);
    float v[8] = {a.x, a.y, a.z, a.w, c.x, c.y, c.z, c.w};

    float s = 0.f;
#pragma unroll
    for (int j = 0; j < 8; ++j) s += v[j];
#pragma unroll
    for (int o = 1; o < 64; o <<= 1) s += __shfl_xor(s, o, 64);
    const float mu = s * (1.0f / D_);

    float s2 = 0.f;
#pragma unroll
    for (int j = 0; j < 8; ++j) { float d = v[j] - mu; s2 += d * d; }
#pragma unroll
    for (int o = 1; o < 64; o <<= 1) s2 += __shfl_xor(s2, o, 64);
    const float rs = rsqrtf(s2 * (1.0f / D_) + 1e-5f);

    float4 g0 = *(const float4*)(g + c0);
    float4 g1 = *(const float4*)(g + c0 + 4);
    float4 b0 = *(const float4*)(be + c0);
    float4 b1 = *(const float4*)(be + c0 + 4);
    float gg[8] = {g0.x, g0.y, g0.z, g0.w, g1.x, g1.y, g1.z, g1.w};
    float bb[8] = {b0.x, b0.y, b0.z, b0.w, b1.x, b1.y, b1.z, b1.w};

    if constexpr (sizeof(OUT) == 2) {
        bf16x8 o8;
#pragma unroll
        for (int j = 0; j < 8; ++j)
            o8[j] = (__bf16)((v[j] - mu) * rs * gg[j] + bb[j]);
        *(bf16x8*)((__hip_bfloat16*)out + (size_t)row * D_ + c0) = o8;
    } else {
        float* op = (float*)out + (size_t)row * D_ + c0;
        float4 r0, r1;
        r0.x = (v[0]-mu)*rs*gg[0]+bb[0]; r0.y = (v[1]-mu)*rs*gg[1]+bb[1];
        r0.z = (v[2]-mu)*rs*gg[2]+bb[2]; r0.w = (v[3]-mu)*rs*gg[3]+bb[3];
        r1.x = (v[4]-mu)*rs*gg[4]+bb[4]; r1.y = (v[5]-mu)*rs*gg[5]+bb[5];
        r1.z = (v[6]-mu)*rs*gg[6]+bb[6]; r1.w = (v[7]-mu)*rs*gg[7]+bb[7];
        *(float4*)op = r0; *(float4*)(op + 4) = r1;
    }
}

// ---------------------------------------------------------------------------
// gemm8: C[M][N] = A[M][K] @ BT[N][K]^T + bias. BM=256 BN=128 BK=64,
// 8 waves (4Mx2N, 64x64 each). T-stack: T1 XCD swizzle, T2 XOR-swizzled LDS
// (pre-swizzled global source, linear gload dest, swizzled ds_read), T3/T4
// 2 phases/K-tile with counted vmcnt(3) (raw s_barrier, no __syncthreads),
// T5 setprio around MFMA clusters.
// EPI: 1 = f32 residual add (out0==Res buffer); 2 = exact GELU -> bf16;
//      4 = fused QKV epilogue (out0=q bf16, out1=k bf16, out2=VT[b][d][l]).
// ---------------------------------------------------------------------------
template <int EPI>
__global__ __launch_bounds__(512) void gemm8(
    const __hip_bfloat16* __restrict__ A,
    const __hip_bfloat16* __restrict__ BT,
    const float* __restrict__ bias0, const float* __restrict__ bias1,
    const float* __restrict__ bias2,
    void* __restrict__ out0, void* __restrict__ out1, void* __restrict__ out2,
    const float* __restrict__ Res, int Ndim, int K)
{
    __shared__ __align__(16) __hip_bfloat16 As[2][256 * 64];   // 2 x 32 KiB
    __shared__ __align__(16) __hip_bfloat16 Bs[2][128 * 64];   // 2 x 16 KiB

    const int tid = threadIdx.x;
    const int w = tid >> 6, lane = tid & 63;
    const int lq = lane & 15, lg = lane >> 4;

    // T1: bijective XCD swizzle (all grids here have nwg % 8 == 0)
    const int gX = gridDim.x;
    const int nwg = gX * gridDim.y;
    int flat = blockIdx.y * gX + blockIdx.x;
    {
        const int qq = nwg >> 3, rr = nwg & 7;
        const int xcd = flat & 7, off = flat >> 3;
        flat = (xcd < rr ? xcd * (qq + 1) : rr * (qq + 1) + (xcd - rr) * qq) + off;
    }
    const int bx = flat % gX, by = flat / gX;
    const int m0 = by * 256, n0 = bx * 128;
    const int wr = (w >> 1) * 64, wc = (w & 1) * 64;

    // staging: gload g covers rows [g*64, g*64+64); this thread handles
    // row r_l within the block, 16B slot (lane&7), source chunk pre-swizzled.
    const int r_l = w * 8 + (lane >> 3);
    const int sw  = (lane & 7) ^ (r_l & 7);
    const __hip_bfloat16* gA = A  + (size_t)(m0 + r_l) * K + sw * 8;
    const __hip_bfloat16* gB = BT + (size_t)(n0 + r_l) * K + sw * 8;

    // swizzled read offsets (bytes): row*128 + ((h*4+lg)^(row&7))*16; h1 = ^64
    const int aoff = (wr + lq) * 128 + ((lg ^ (lq & 7)) << 4);
    const int boff = (wc + lq) * 128 + ((lg ^ (lq & 7)) << 4);

    f32x4 acc[4][4] = {};
    const int NT = K >> 6;

    {   // prologue: stage tile 0 into buf 0
        char* nA = (char*)As[0] + w * 1024;
        char* nB = (char*)Bs[0] + w * 1024;
        GLD16(gA,                  nA);
        GLD16(gA + (size_t)64 * K, nA + 8192);
        GLD16(gA + (size_t)128 * K, nA + 16384);
        GLD16(gA + (size_t)192 * K, nA + 24576);
        GLD16(gB,                  nB);
        GLD16(gB + (size_t)64 * K, nB + 8192);
    }

    int cur = 0;
    for (int t = 0; t < NT; ++t) {
        char* cA = (char*)As[cur];
        char* cB = (char*)Bs[cur];
        char* nA = (char*)As[cur ^ 1] + w * 1024;
        char* nB = (char*)Bs[cur ^ 1] + w * 1024;
        const size_t ko = (size_t)(t + 1) * 64;
        const bool pf = (t + 1 < NT);

        // ---- phase 0: issue A0-A2 of t+1, counted wait for tile t ----
        if (pf) {
            GLD16(gA + ko,                   nA);
            GLD16(gA + (size_t)64 * K + ko,  nA + 8192);
            GLD16(gA + (size_t)128 * K + ko, nA + 16384);
            asm volatile("s_waitcnt vmcnt(3)" ::: "memory");
        } else {
            asm volatile("s_waitcnt vmcnt(0)" ::: "memory");
        }
        __builtin_amdgcn_s_barrier();          // tile t visible to all waves
        __builtin_amdgcn_sched_barrier(0);
        {
            bf16x8 af[4], bf[4];
#pragma unroll
            for (int i = 0; i < 4; ++i) af[i] = *(const bf16x8*)(cA + i * 2048 + aoff);
#pragma unroll
            for (int j = 0; j < 4; ++j) bf[j] = *(const bf16x8*)(cB + j * 2048 + boff);
            __builtin_amdgcn_s_setprio(1);
#pragma unroll
            for (int i = 0; i < 4; ++i)
#pragma unroll
                for (int j = 0; j < 4; ++j)
                    acc[i][j] = MFMA16(af[i], bf[j], acc[i][j]);
            __builtin_amdgcn_s_setprio(0);
        }
        __builtin_amdgcn_s_barrier();

        // ---- phase 1: issue A3,B0,B1 of t+1; compute k-half 1 ----
        if (pf) {
            GLD16(gA + (size_t)192 * K + ko, nA + 24576);
            GLD16(gB + ko,                   nB);
            GLD16(gB + (size_t)64 * K + ko,  nB + 8192);
        }
        {
            bf16x8 af[4], bf[4];
#pragma unroll
            for (int i = 0; i < 4; ++i) af[i] = *(const bf16x8*)(cA + i * 2048 + (aoff ^ 64));
#pragma unroll
            for (int j = 0; j < 4; ++j) bf[j] = *(const bf16x8*)(cB + j * 2048 + (boff ^ 64));
            __builtin_amdgcn_s_barrier();
            __builtin_amdgcn_s_setprio(1);
#pragma unroll
            for (int i = 0; i < 4; ++i)
#pragma unroll
                for (int j = 0; j < 4; ++j)
                    acc[i][j] = MFMA16(af[i], bf[j], acc[i][j]);
            __builtin_amdgcn_s_setprio(0);
        }
        __builtin_amdgcn_s_barrier();
        cur ^= 1;
    }

    // ---- epilogue ----
    if constexpr (EPI == 4) {
        const int sec = n0 >> 9;                 // 0=q, 1=k, 2=v
        const int nb = (n0 & 511) + wc;
        const float* bp = sec == 0 ? bias0 : (sec == 1 ? bias1 : bias2);
        float bcol[4];
#pragma unroll
        for (int j = 0; j < 4; ++j) bcol[j] = bp[nb + j * 16 + lq];
        if (sec < 2) {
            __hip_bfloat16* op = (__hip_bfloat16*)(sec == 0 ? out0 : out1);
#pragma unroll
            for (int i = 0; i < 4; ++i)
#pragma unroll
                for (int j = 0; j < 4; ++j)
#pragma unroll
                    for (int r = 0; r < 4; ++r) {
                        const int m = m0 + wr + i * 16 + lg * 4 + r;
                        op[(size_t)m * 512 + nb + j * 16 + lq] =
                            __float2bfloat16(acc[i][j][r] + bcol[j]);
                    }
        } else {
            __hip_bfloat16* vp = (__hip_bfloat16*)out2;
            const int bb = m0 >> 9;
            const int l0 = (m0 & 511) + wr + lg * 4;
#pragma unroll
            for (int i = 0; i < 4; ++i)
#pragma unroll
                for (int j = 0; j < 4; ++j) {
                    bf16x4 pv;
#pragma unroll
                    for (int r = 0; r < 4; ++r)
                        pv[r] = (__bf16)(acc[i][j][r] + bcol[j]);
                    *(bf16x4*)(vp + ((size_t)(bb * 512 + nb + j * 16 + lq)) * 512
                               + l0 + i * 16) = pv;
                }
        }
    } else {
        float bcol[4];
#pragma unroll
        for (int j = 0; j < 4; ++j) bcol[j] = bias0[n0 + wc + j * 16 + lq];
#pragma unroll
        for (int i = 0; i < 4; ++i)
#pragma unroll
            for (int j = 0; j < 4; ++j) {
                const int n = n0 + wc + j * 16 + lq;
#pragma unroll
                for (int r = 0; r < 4; ++r) {
                    const int m = m0 + wr + i * 16 + lg * 4 + r;
                    float v = acc[i][j][r] + bcol[j];
                    if constexpr (EPI == 1) {
                        float* Co = (float*)out0;
                        const size_t idx = (size_t)m * Ndim + n;
                        Co[idx] = Res[idx] + v;
                    } else {  // EPI == 2
                        float gl = 0.5f * v * (1.0f + erff(v * 0.70710678118654752f));
                        ((__hip_bfloat16*)out0)[(size_t)m * Ndim + n] = __float2bfloat16(gl);
                    }
                }
            }
    }
}

// ---------------------------------------------------------------------------
// Flash attention: 4 waves/block, 64 q-rows/block, KV tiles of 64,
// K/V double-buffered in LDS (pre-swizzled global_load_lds source).
// ---------------------------------------------------------------------------
__global__ __launch_bounds__(256) void attn_kernel(
    const __hip_bfloat16* __restrict__ Q, const __hip_bfloat16* __restrict__ K,
    const __hip_bfloat16* __restrict__ VT, __hip_bfloat16* __restrict__ Out,
    const int* __restrict__ case_ids, const int* __restrict__ amask,
    const float* __restrict__ case_bias, const float* __restrict__ verb_bias,
    int layer)
{
    __shared__ __align__(16) __bf16 Ks[2][64 * 64];
    __shared__ __align__(16) __bf16 Vs[2][64 * 64];
    __shared__ __align__(16) __bf16 Pl[4][16 * 64];
    __shared__ __bf16 Bia[9][520];

    const int bh = blockIdx.x;
    const int b = bh >> 3, hh = bh & 7;
    const int qc = blockIdx.y;
    const int t = threadIdx.x;
    const int w = t >> 6, lane = t & 63;
    const int lq = lane & 15, lg = lane >> 4;
    const int swz = lq & 7;

    const int rA = w * 16 + (lane >> 3);
    const int swsrc = ((lane & 7) ^ (lane >> 3)) << 4;
    const __hip_bfloat16* kg0 = K  + ((size_t)b * L_ + rA) * D_ + hh * HD_;
    const __hip_bfloat16* vg0 = VT + ((size_t)b * D_ + hh * HD_ + rA) * L_;

    auto stage = [&](int buf, int kv0) {
        const char* gk = (const char*)(kg0 + (size_t)kv0 * D_) + swsrc;
        GLD16(gk,                      (char*)Ks[buf] + w * 2048);
        GLD16(gk + (size_t)8 * D_ * 2, (char*)Ks[buf] + w * 2048 + 1024);
        const char* gv = (const char*)(vg0 + kv0) + swsrc;
        GLD16(gv,                      (char*)Vs[buf] + w * 2048);
        GLD16(gv + (size_t)8 * L_ * 2, (char*)Vs[buf] + w * 2048 + 1024);
    };

    stage(0, 0);

    const float vb = verb_bias[layer * H_ + hh];
    const float* cb = case_bias + ((size_t)layer * H_ + hh) * (C_ * C_);
    for (int idx = t; idx < 9 * 512; idx += 256) {
        const int ci = idx >> 9, kv = idx & 511;
        const int cj = case_ids[b * L_ + kv];
        Bia[ci][kv] = (__bf16)(cb[ci * C_ + cj] + (cj == 8 ? vb : 0.f)
                               - 10000.f * (1.f - (float)amask[b * L_ + kv]));
    }
    __syncthreads();

    const int qloc = w * 16 + lq;
    const int qrow = qc * 64 + qloc;
    const int ci_q = case_ids[b * L_ + qrow];
    const __hip_bfloat16* qp = Q + ((size_t)b * L_ + qrow) * D_ + hh * HD_;
    const bf16x8 qf0 = *(const bf16x8*)(qp + lg * 8);
    const bf16x8 qf1 = *(const bf16x8*)(qp + 32 + lg * 8);

    float m_run = -1e30f, l_run = 0.f;
    f32x4 o[4] = {};
    const int ntiles = qc + 1;
    int cur = 0;

    for (int kt = 0; kt < ntiles; ++kt) {
        if (kt + 1 < ntiles) stage(cur ^ 1, (kt + 1) * 64);

        const char* kb  = (const char*)Ks[cur];
        const char* vb2 = (const char*)Vs[cur];

        f32x4 s[4] = {};
        __builtin_amdgcn_s_setprio(1);
#pragma unroll
        for (int c = 0; c < 4; ++c) {
            const bf16x8 ka = *(const bf16x8*)(kb + (16 * c + lq) * 128 + ((lg ^ swz) << 4));
            s[c] = MFMA16(ka, qf0, s[c]);
            const bf16x8 kc = *(const bf16x8*)(kb + (16 * c + lq) * 128 + (((4 + lg) ^ swz) << 4));
            s[c] = MFMA16(kc, qf1, s[c]);
        }
        __builtin_amdgcn_s_setprio(0);

        const __bf16* brow = &Bia[ci_q][kt * 64];
        const bool dtile = (kt == qc);
        float xs[16];
#pragma unroll
        for (int c = 0; c < 4; ++c) {
            const bf16x4 bb = *(const bf16x4*)(brow + 16 * c + lg * 4);
#pragma unroll
            for (int r = 0; r < 4; ++r) {
                const int kvl = 16 * c + lg * 4 + r;
                float v = s[c][r] * 0.125f + (float)bb[r];
                xs[4 * c + r] = (dtile && (kvl > qloc)) ? -1e9f : v;
            }
        }

        float a0 = fmaxf(fmaxf(xs[0], xs[1]),  fmaxf(xs[2], xs[3]));
        float a1 = fmaxf(fmaxf(xs[4], xs[5]),  fmaxf(xs[6], xs[7]));
        float a2 = fmaxf(fmaxf(xs[8], xs[9]),  fmaxf(xs[10], xs[11]));
        float a3 = fmaxf(fmaxf(xs[12], xs[13]), fmaxf(xs[14], xs[15]));
        float pmax = fmaxf(fmaxf(a0, a1), fmaxf(a2, a3));
        pmax = fmaxf(pmax, __shfl_xor(pmax, 16, 64));
        pmax = fmaxf(pmax, __shfl_xor(pmax, 32, 64));

        const float mnew = fmaxf(m_run, pmax);
        const float corr = __expf(m_run - mnew);
        float p[16], ps0 = 0.f, ps1 = 0.f;
#pragma unroll
        for (int j = 0; j < 16; j += 2) {
            p[j]     = __expf(xs[j] - mnew);     ps0 += p[j];
            p[j + 1] = __expf(xs[j + 1] - mnew); ps1 += p[j + 1];
        }
        float ps = ps0 + ps1;
        ps += __shfl_xor(ps, 16, 64);
        ps += __shfl_xor(ps, 32, 64);
        l_run = l_run * corr + ps;
        m_run = mnew;

        float cr[4];
#pragma unroll
        for (int r = 0; r < 4; ++r) cr[r] = __shfl(corr, lg * 4 + r, 64);
#pragma unroll
        for (int nt = 0; nt < 4; ++nt)
#pragma unroll
            for (int r = 0; r < 4; ++r) o[nt][r] *= cr[r];

        char* pw = (char*)Pl[w];
#pragma unroll
        for (int c = 0; c < 4; ++c) {
            bf16x4 pv;
#pragma unroll
            for (int r = 0; r < 4; ++r) pv[r] = (__bf16)p[4 * c + r];
            const int slot = (2 * c + (lg >> 1)) ^ swz;
            *(bf16x4*)(pw + lq * 128 + (slot << 4) + ((lg & 1) << 3)) = pv;
        }

        __builtin_amdgcn_s_setprio(1);
#pragma unroll
        for (int hf = 0; hf < 2; ++hf) {
            const bf16x8 pf = *(const bf16x8*)(pw + lq * 128 + (((hf * 4 + lg) ^ swz) << 4));
#pragma unroll
            for (int nt = 0; nt < 4; ++nt) {
                const bf16x8 vf = *(const bf16x8*)(vb2 + (nt * 16 + lq) * 128
                                                   + (((hf * 4 + lg) ^ swz) << 4));
                o[nt] = MFMA16(pf, vf, o[nt]);
            }
        }
        __builtin_amdgcn_s_setprio(0);

        __syncthreads();
        cur ^= 1;
    }

    const float inv = 1.f / l_run;
    float ir[4];
#pragma unroll
    for (int r = 0; r < 4; ++r) ir[r] = __shfl(inv, lg * 4 + r, 64);
    __hip_bfloat16* op = Out + ((size_t)b * L_ + qc * 64 + w * 16) * D_ + hh * HD_;
#pragma unroll
    for (int nt = 0; nt < 4; ++nt)
#pragma unroll
        for (int r = 0; r < 4; ++r)
            op[(size_t)(lg * 4 + r) * D_ + nt * 16 + lq] = __float2bfloat16(o[nt][r] * ir[r]);
}

// ---------------------------------------------------------------------------
extern "C" void kernel_launch(void* const* d_in, const int* in_sizes, int n_in,
                              void* d_out, int out_size, void* d_ws, size_t ws_size,
                              hipStream_t stream)
{
    const float* x_in  = (const float*)d_in[0];
    const int*   cids  = (const int*)  d_in[1];
    const int*   amask = (const int*)  d_in[2];
    const float* Wq = (const float*)d_in[3];
    const float* bq = (const float*)d_in[4];
    const float* Wk = (const float*)d_in[5];
    const float* bk = (const float*)d_in[6];
    const float* Wv = (const float*)d_in[7];
    const float* bv = (const float*)d_in[8];
    const float* Wo = (const float*)d_in[9];
    const float* bo = (const float*)d_in[10];
    const float* ln1g = (const float*)d_in[11];
    const float* ln1b = (const float*)d_in[12];
    const float* ln2g = (const float*)d_in[13];
    const float* ln2b = (const float*)d_in[14];
    const float* W1 = (const float*)d_in[15];
    const float* b1 = (const float*)d_in[16];
    const float* W2 = (const float*)d_in[17];
    const float* b2 = (const float*)d_in[18];
    const float* cbias = (const float*)d_in[19];
    const float* vbias = (const float*)d_in[20];
    const float* fng = (const float*)d_in[21];
    const float* fnb = (const float*)d_in[22];

    char* w = (char*)d_ws;
    float* x_ws = (float*)w;                 w += (size_t)MTOK * D_ * 4;
    __hip_bfloat16* hbuf = (__hip_bfloat16*)w; w += (size_t)MTOK * D_ * 2;
    __hip_bfloat16* qbuf = (__hip_bfloat16*)w; w += (size_t)MTOK * D_ * 2;
    __hip_bfloat16* kbuf = (__hip_bfloat16*)w; w += (size_t)MTOK * D_ * 2;
    __hip_bfloat16* vtb  = (__hip_bfloat16*)w; w += (size_t)MTOK * D_ * 2;
    __hip_bfloat16* ffb  = (__hip_bfloat16*)w; w += (size_t)MTOK * F_ * 2;
    __hip_bfloat16* WqkvT = (__hip_bfloat16*)w; w += (size_t)NL_ * 3 * D_ * D_ * 2;
    __hip_bfloat16* WoT  = (__hip_bfloat16*)w; w += (size_t)NL_ * D_ * D_ * 2;
    __hip_bfloat16* W1T  = (__hip_bfloat16*)w; w += (size_t)NL_ * D_ * F_ * 2;
    __hip_bfloat16* W2T  = (__hip_bfloat16*)w; w += (size_t)NL_ * D_ * F_ * 2;

    const size_t qkvZ = (size_t)3 * D_ * D_;     // per-layer stride in WqkvT
    const dim3 tb(32, 8);
    transpose_w<<<dim3(D_/32, D_/32, NL_), tb, 0, stream>>>(Wq, WqkvT,             D_, D_, qkvZ);
    transpose_w<<<dim3(D_/32, D_/32, NL_), tb, 0, stream>>>(Wk, WqkvT + D_*D_,     D_, D_, qkvZ);
    transpose_w<<<dim3(D_/32, D_/32, NL_), tb, 0, stream>>>(Wv, WqkvT + 2*D_*D_,   D_, D_, qkvZ);
    transpose_w<<<dim3(D_/32, D_/32, NL_), tb, 0, stream>>>(Wo, WoT, D_, D_, (size_t)D_*D_);
    transpose_w<<<dim3(F_/32, D_/32, NL_), tb, 0, stream>>>(W1, W1T, D_, F_, (size_t)D_*F_);
    transpose_w<<<dim3(D_/32, F_/32, NL_), tb, 0, stream>>>(W2, W2T, F_, D_, (size_t)D_*F_);

    copy_f32x4<<<8192, 256, 0, stream>>>((const float4*)x_in, (float4*)x_ws,
                                         MTOK * D_ / 4);

    const dim3 gQKV(12, 64);   // N=1536
    const dim3 gO(4, 64);      // N=512
    const dim3 gW1(16, 64);    // N=2048
    const dim3 gW2(4, 64);     // N=512

    for (int i = 0; i < NL_; ++i) {
        ln_kernel<__hip_bfloat16><<<MTOK/4, 256, 0, stream>>>(
            x_ws, ln1g + i * D_, ln1b + i * D_, hbuf);

        gemm8<4><<<gQKV, 512, 0, stream>>>(hbuf, WqkvT + (size_t)i * qkvZ,
            bq + i*D_, bk + i*D_, bv + i*D_, qbuf, kbuf, vtb, nullptr, 512, D_);

        attn_kernel<<<dim3(B_ * H_, L_/64), 256, 0, stream>>>(
            qbuf, kbuf, vtb, hbuf, cids, amask, cbias, vbias, i);

        gemm8<1><<<gO, 512, 0, stream>>>(hbuf, WoT + (size_t)i*D_*D_,
            bo + i*D_, nullptr, nullptr, x_ws, nullptr, nullptr, x_ws, D_, D_);

        ln_kernel<__hip_bfloat16><<<MTOK/4, 256, 0, stream>>>(
            x_ws, ln2g + i * D_, ln2b + i * D_, hbuf);

        gemm8<2><<<gW1, 512, 0, stream>>>(hbuf, W1T + (size_t)i*D_*F_,
            b1 + i*F_, nullptr, nullptr, ffb, nullptr, nullptr, nullptr, F_, D_);

        gemm8<1><<<gW2, 512, 0, stream>>>(ffb, W2T + (size_t)i*D_*F_,
            b2 + i*D_, nullptr, nullptr, x_ws, nullptr, nullptr, x_ws, D_, F_);
    }

    ln_kernel<float><<<MTOK/4, 256, 0, stream>>>(x_ws, fng, fnb, (float*)d_out);
}

// Round 4
// 1403.817 us; speedup vs baseline: 1.7564x; 1.2196x over previous
//
#include <hip/hip_runtime.h>
#include <hip/hip_bf16.h>

// Problem constants
#define B_   32
#define L_   512
#define D_   512
#define H_   8
#define NL_  6
#define F_   2048
#define C_   9
#define HD_  64
#define MTOK 16384   // B_*L_

typedef __bf16 bf16x8 __attribute__((ext_vector_type(8)));
typedef __bf16 bf16x4 __attribute__((ext_vector_type(4)));
typedef float  f32x4  __attribute__((ext_vector_type(4)));

#define MFMA16(a,b,c) __builtin_amdgcn_mfma_f32_16x16x32_bf16((a),(b),(c),0,0,0)
#define GLD16(g,l) __builtin_amdgcn_global_load_lds( \
    (const __attribute__((address_space(1))) void*)(g), \
    (__attribute__((address_space(3))) void*)(l), 16, 0, 0)

// ---------------------------------------------------------------------------
// Weight transpose + f32->bf16: in [z][K][N] f32 -> out [z-stride zso][N][K]
// ---------------------------------------------------------------------------
__global__ __launch_bounds__(256) void transpose_w(
    const float* __restrict__ in, __hip_bfloat16* __restrict__ out,
    int K, int N, size_t zso)
{
    __shared__ float t[32][33];
    const int z = blockIdx.z;
    const float* src = in + (size_t)z * K * N;
    __hip_bfloat16* dst = out + (size_t)z * zso;
    const int n0 = blockIdx.x * 32, k0 = blockIdx.y * 32;
    const int tx = threadIdx.x, ty = threadIdx.y;   // (32,8)
#pragma unroll
    for (int r = ty; r < 32; r += 8)
        t[r][tx] = src[(size_t)(k0 + r) * N + n0 + tx];
    __syncthreads();
#pragma unroll
    for (int r = ty; r < 32; r += 8)
        dst[(size_t)(n0 + r) * K + k0 + tx] = __float2bfloat16(t[tx][r]);
}

// ---------------------------------------------------------------------------
__global__ void copy_f32x4(const float4* __restrict__ in, float4* __restrict__ out, int n)
{
    int i = blockIdx.x * blockDim.x + threadIdx.x;
    if (i < n) out[i] = in[i];
}

// ---------------------------------------------------------------------------
// LayerNorm: one wave per row (D=512 -> 8 f32/lane). OUT = bf16 or f32.
// ---------------------------------------------------------------------------
template <typename OUT>
__global__ __launch_bounds__(256) void ln_kernel(
    const float* __restrict__ x, const float* __restrict__ g,
    const float* __restrict__ be, OUT* __restrict__ out)
{
    const int row  = blockIdx.x * 4 + (threadIdx.x >> 6);
    const int lane = threadIdx.x & 63;
    const int c0   = lane * 8;
    const float* xr = x + (size_t)row * D_ + c0;
    float4 a = *(const float4*)xr;
    float4 c = *(const float4*)(xr + 4);
    float v[8] = {a.x, a.y, a.z, a.w, c.x, c.y, c.z, c.w};

    float s = 0.f;
#pragma unroll
    for (int j = 0; j < 8; ++j) s += v[j];
#pragma unroll
    for (int o = 1; o < 64; o <<= 1) s += __shfl_xor(s, o, 64);
    const float mu = s * (1.0f / D_);

    float s2 = 0.f;
#pragma unroll
    for (int j = 0; j < 8; ++j) { float d = v[j] - mu; s2 += d * d; }
#pragma unroll
    for (int o = 1; o < 64; o <<= 1) s2 += __shfl_xor(s2, o, 64);
    const float rs = rsqrtf(s2 * (1.0f / D_) + 1e-5f);

    float4 g0 = *(const float4*)(g + c0);
    float4 g1 = *(const float4*)(g + c0 + 4);
    float4 b0 = *(const float4*)(be + c0);
    float4 b1 = *(const float4*)(be + c0 + 4);
    float gg[8] = {g0.x, g0.y, g0.z, g0.w, g1.x, g1.y, g1.z, g1.w};
    float bb[8] = {b0.x, b0.y, b0.z, b0.w, b1.x, b1.y, b1.z, b1.w};

    if constexpr (sizeof(OUT) == 2) {
        bf16x8 o8;
#pragma unroll
        for (int j = 0; j < 8; ++j)
            o8[j] = (__bf16)((v[j] - mu) * rs * gg[j] + bb[j]);
        *(bf16x8*)((__hip_bfloat16*)out + (size_t)row * D_ + c0) = o8;
    } else {
        float* op = (float*)out + (size_t)row * D_ + c0;
        float4 r0, r1;
        r0.x = (v[0]-mu)*rs*gg[0]+bb[0]; r0.y = (v[1]-mu)*rs*gg[1]+bb[1];
        r0.z = (v[2]-mu)*rs*gg[2]+bb[2]; r0.w = (v[3]-mu)*rs*gg[3]+bb[3];
        r1.x = (v[4]-mu)*rs*gg[4]+bb[4]; r1.y = (v[5]-mu)*rs*gg[5]+bb[5];
        r1.z = (v[6]-mu)*rs*gg[6]+bb[6]; r1.w = (v[7]-mu)*rs*gg[7]+bb[7];
        *(float4*)op = r0; *(float4*)(op + 4) = r1;
    }
}

// ---------------------------------------------------------------------------
// gemm_p: deep-pipelined GEMM. C[M][N] = A[M][K] @ BT[N][K]^T + bias.
// BK=32, 4 LDS buffers (stage tile t+3 while computing t), one s_barrier and
// one counted vmcnt per K-tile (never drained in-loop). 8 waves, 512 thr.
//   WNW=4: BM=256 BN=256, waves 2Mx4N, per-wave 128x64 (FM=8)  [QKV, W1]
//   WNW=2: BM=256 BN=128, waves 4Mx2N, per-wave  64x64 (FM=4)  [O, W2]
// LDS chunk-swizzle: stored 16B-chunk c holds global chunk c^((row>>1)&3)
// -> 2-way max bank aliasing (free). Same involution on read side.
// EPI: 1 = f32 residual add (out0==Res); 2 = exact GELU -> bf16;
//      4 = fused QKV epilogue (out0=q, out1=k, out2=VT[b][d][l]).
// ---------------------------------------------------------------------------
template <int EPI, int WNW>
__global__ __launch_bounds__(512, 2) void gemm_p(
    const __hip_bfloat16* __restrict__ A,
    const __hip_bfloat16* __restrict__ BT,
    const float* __restrict__ bias0, const float* __restrict__ bias1,
    const float* __restrict__ bias2,
    void* __restrict__ out0, void* __restrict__ out1, void* __restrict__ out2,
    const float* __restrict__ Res, int Ndim, int K)
{
    constexpr int FM = (WNW == 4) ? 8 : 4;     // m-frags per wave
    constexpr int BN = WNW * 64;
    constexpr int BLOADS = BN / 128;           // B GLD16s per thread per tile
    __shared__ __align__(16) __hip_bfloat16 As[4][256 * 32];
    __shared__ __align__(16) __hip_bfloat16 Bs[4][BN * 32];

    const int tid = threadIdx.x;
    const int w = tid >> 6, lane = tid & 63;
    const int lq = lane & 15, lg = lane >> 4;

    // T1: bijective XCD swizzle (nwg % 8 == 0 for all launches here)
    const int gX = gridDim.x;
    const int nwg = gX * gridDim.y;
    int flat = blockIdx.y * gX + blockIdx.x;
    {
        const int qq = nwg >> 3, rr = nwg & 7;
        const int xcd = flat & 7, off = flat >> 3;
        flat = (xcd < rr ? xcd * (qq + 1) : rr * (qq + 1) + (xcd - rr) * qq) + off;
    }
    const int bx = flat % gX, by = flat / gX;
    const int m0 = by * 256, n0 = bx * BN;
    const int wm = w / WNW, wn = w % WNW;
    const int RB = wm * (FM * 16);             // wave row base in tile
    const int CB = wn * 64;                    // wave col base in tile

    // ---- staging geometry (pre-swizzled source, linear LDS dest) ----
    const int sr = lane >> 2;                                  // 0..15
    const int sc = ((lane & 3) ^ ((lane >> 3) & 3)) * 8;       // element off
    const __hip_bfloat16* gA0 = A + (size_t)(m0 + (w*2+0)*16 + sr) * K + sc;
    const __hip_bfloat16* gA1 = A + (size_t)(m0 + (w*2+1)*16 + sr) * K + sc;
    const __hip_bfloat16* gB0;
    const __hip_bfloat16* gB1 = nullptr;
    if constexpr (BLOADS == 2) {
        gB0 = BT + (size_t)(n0 + (w*2+0)*16 + sr) * K + sc;
        gB1 = BT + (size_t)(n0 + (w*2+1)*16 + sr) * K + sc;
    } else {
        gB0 = BT + (size_t)(n0 + w*16 + sr) * K + sc;
    }

    auto STAGE = [&](int tt) {
        const size_t ko = (size_t)tt * 32;
        char* ab = (char*)As[tt & 3];
        GLD16(gA0 + ko, ab + (w*2+0) * 1024);
        GLD16(gA1 + ko, ab + (w*2+1) * 1024);
        char* bb = (char*)Bs[tt & 3];
        if constexpr (BLOADS == 2) {
            GLD16(gB0 + ko, bb + (w*2+0) * 1024);
            GLD16(gB1 + ko, bb + (w*2+1) * 1024);
        } else {
            GLD16(gB0 + ko, bb + w * 1024);
        }
    };

    // ---- fragment read offsets (bytes), chunk-swizzled ----
    const int rsw = (lq >> 1) & 3;
    const int aoff = (RB + lq) * 64 + ((lg ^ rsw) << 4);
    const int boff = (CB + lq) * 64 + ((lg ^ rsw) << 4);

    f32x4 acc[FM][4] = {};
    const int NTt = K >> 5;

    STAGE(0); STAGE(1); STAGE(2);

    for (int t = 0; t < NTt; ++t) {
        // counted wait: tile t landed; up to 2 tiles (t+1,t+2) in flight
        if (t < NTt - 2) {
            if constexpr (BLOADS == 2) asm volatile("s_waitcnt vmcnt(8)" ::: "memory");
            else                       asm volatile("s_waitcnt vmcnt(6)" ::: "memory");
        } else if (t < NTt - 1) {
            if constexpr (BLOADS == 2) asm volatile("s_waitcnt vmcnt(4)" ::: "memory");
            else                       asm volatile("s_waitcnt vmcnt(3)" ::: "memory");
        } else {
            asm volatile("s_waitcnt vmcnt(0)" ::: "memory");
        }
        __builtin_amdgcn_s_barrier();
        __builtin_amdgcn_sched_barrier(0);

        const char* ca = (const char*)As[t & 3];
        const char* cb = (const char*)Bs[t & 3];
        bf16x8 bf[4];
#pragma unroll
        for (int fn = 0; fn < 4; ++fn) bf[fn] = *(const bf16x8*)(cb + boff + fn * 1024);
        bf16x8 af[FM];
#pragma unroll
        for (int fm = 0; fm < FM; ++fm) af[fm] = *(const bf16x8*)(ca + aoff + fm * 1024);

        if (t + 3 < NTt) STAGE(t + 3);   // targets buf (t-1)&3: freed at barrier

        __builtin_amdgcn_s_setprio(1);
#pragma unroll
        for (int fm = 0; fm < FM; ++fm)
#pragma unroll
            for (int fn = 0; fn < 4; ++fn)
                acc[fm][fn] = MFMA16(af[fm], bf[fn], acc[fm][fn]);
        __builtin_amdgcn_s_setprio(0);
    }

    // ---- epilogue ----
    if constexpr (EPI == 4) {
        const int sec = n0 >> 9;                 // 0=q, 1=k, 2=v
        const int nb = (n0 & 511) + CB;
        const float* bp = sec == 0 ? bias0 : (sec == 1 ? bias1 : bias2);
        float bcol[4];
#pragma unroll
        for (int fn = 0; fn < 4; ++fn) bcol[fn] = bp[nb + fn * 16 + lq];
        if (sec < 2) {
            __hip_bfloat16* op = (__hip_bfloat16*)(sec == 0 ? out0 : out1);
#pragma unroll
            for (int fm = 0; fm < FM; ++fm)
#pragma unroll
                for (int fn = 0; fn < 4; ++fn)
#pragma unroll
                    for (int r = 0; r < 4; ++r) {
                        const int m = m0 + RB + fm * 16 + lg * 4 + r;
                        op[(size_t)m * 512 + nb + fn * 16 + lq] =
                            __float2bfloat16(acc[fm][fn][r] + bcol[fn]);
                    }
        } else {
            __hip_bfloat16* vp = (__hip_bfloat16*)out2;
            const int bb = m0 >> 9;
            const int l0 = (m0 & 511) + RB + lg * 4;
#pragma unroll
            for (int fm = 0; fm < FM; ++fm)
#pragma unroll
                for (int fn = 0; fn < 4; ++fn) {
                    bf16x4 pv;
#pragma unroll
                    for (int r = 0; r < 4; ++r)
                        pv[r] = (__bf16)(acc[fm][fn][r] + bcol[fn]);
                    *(bf16x4*)(vp + ((size_t)(bb * 512 + nb + fn * 16 + lq)) * 512
                               + l0 + fm * 16) = pv;
                }
        }
    } else {
        float bcol[4];
#pragma unroll
        for (int fn = 0; fn < 4; ++fn) bcol[fn] = bias0[n0 + CB + fn * 16 + lq];
#pragma unroll
        for (int fm = 0; fm < FM; ++fm)
#pragma unroll
            for (int fn = 0; fn < 4; ++fn) {
                const int n = n0 + CB + fn * 16 + lq;
#pragma unroll
                for (int r = 0; r < 4; ++r) {
                    const int m = m0 + RB + fm * 16 + lg * 4 + r;
                    float v = acc[fm][fn][r] + bcol[fn];
                    if constexpr (EPI == 1) {
                        float* Co = (float*)out0;
                        const size_t idx = (size_t)m * Ndim + n;
                        Co[idx] = Res[idx] + v;
                    } else {  // EPI == 2
                        float gl = 0.5f * v * (1.0f + erff(v * 0.70710678118654752f));
                        ((__hip_bfloat16*)out0)[(size_t)m * Ndim + n] = __float2bfloat16(gl);
                    }
                }
            }
    }
}

// ---------------------------------------------------------------------------
// Flash attention: 4 waves/block, 64 q-rows/block, KV tiles of 64,
// K/V double-buffered in LDS (pre-swizzled global_load_lds source).
// ---------------------------------------------------------------------------
__global__ __launch_bounds__(256) void attn_kernel(
    const __hip_bfloat16* __restrict__ Q, const __hip_bfloat16* __restrict__ K,
    const __hip_bfloat16* __restrict__ VT, __hip_bfloat16* __restrict__ Out,
    const int* __restrict__ case_ids, const int* __restrict__ amask,
    const float* __restrict__ case_bias, const float* __restrict__ verb_bias,
    int layer)
{
    __shared__ __align__(16) __bf16 Ks[2][64 * 64];
    __shared__ __align__(16) __bf16 Vs[2][64 * 64];
    __shared__ __align__(16) __bf16 Pl[4][16 * 64];
    __shared__ __bf16 Bia[9][520];

    const int bh = blockIdx.x;
    const int b = bh >> 3, hh = bh & 7;
    const int qc = blockIdx.y;
    const int t = threadIdx.x;
    const int w = t >> 6, lane = t & 63;
    const int lq = lane & 15, lg = lane >> 4;
    const int swz = lq & 7;

    const int rA = w * 16 + (lane >> 3);
    const int swsrc = ((lane & 7) ^ (lane >> 3)) << 4;
    const __hip_bfloat16* kg0 = K  + ((size_t)b * L_ + rA) * D_ + hh * HD_;
    const __hip_bfloat16* vg0 = VT + ((size_t)b * D_ + hh * HD_ + rA) * L_;

    auto stage = [&](int buf, int kv0) {
        const char* gk = (const char*)(kg0 + (size_t)kv0 * D_) + swsrc;
        GLD16(gk,                      (char*)Ks[buf] + w * 2048);
        GLD16(gk + (size_t)8 * D_ * 2, (char*)Ks[buf] + w * 2048 + 1024);
        const char* gv = (const char*)(vg0 + kv0) + swsrc;
        GLD16(gv,                      (char*)Vs[buf] + w * 2048);
        GLD16(gv + (size_t)8 * L_ * 2, (char*)Vs[buf] + w * 2048 + 1024);
    };

    stage(0, 0);

    const float vb = verb_bias[layer * H_ + hh];
    const float* cb = case_bias + ((size_t)layer * H_ + hh) * (C_ * C_);
    for (int idx = t; idx < 9 * 512; idx += 256) {
        const int ci = idx >> 9, kv = idx & 511;
        const int cj = case_ids[b * L_ + kv];
        Bia[ci][kv] = (__bf16)(cb[ci * C_ + cj] + (cj == 8 ? vb : 0.f)
                               - 10000.f * (1.f - (float)amask[b * L_ + kv]));
    }
    __syncthreads();

    const int qloc = w * 16 + lq;
    const int qrow = qc * 64 + qloc;
    const int ci_q = case_ids[b * L_ + qrow];
    const __hip_bfloat16* qp = Q + ((size_t)b * L_ + qrow) * D_ + hh * HD_;
    const bf16x8 qf0 = *(const bf16x8*)(qp + lg * 8);
    const bf16x8 qf1 = *(const bf16x8*)(qp + 32 + lg * 8);

    float m_run = -1e30f, l_run = 0.f;
    f32x4 o[4] = {};
    const int ntiles = qc + 1;
    int cur = 0;

    for (int kt = 0; kt < ntiles; ++kt) {
        if (kt + 1 < ntiles) stage(cur ^ 1, (kt + 1) * 64);

        const char* kb  = (const char*)Ks[cur];
        const char* vb2 = (const char*)Vs[cur];

        f32x4 s[4] = {};
        __builtin_amdgcn_s_setprio(1);
#pragma unroll
        for (int c = 0; c < 4; ++c) {
            const bf16x8 ka = *(const bf16x8*)(kb + (16 * c + lq) * 128 + ((lg ^ swz) << 4));
            s[c] = MFMA16(ka, qf0, s[c]);
            const bf16x8 kc = *(const bf16x8*)(kb + (16 * c + lq) * 128 + (((4 + lg) ^ swz) << 4));
            s[c] = MFMA16(kc, qf1, s[c]);
        }
        __builtin_amdgcn_s_setprio(0);

        const __bf16* brow = &Bia[ci_q][kt * 64];
        const bool dtile = (kt == qc);
        float xs[16];
#pragma unroll
        for (int c = 0; c < 4; ++c) {
            const bf16x4 bb = *(const bf16x4*)(brow + 16 * c + lg * 4);
#pragma unroll
            for (int r = 0; r < 4; ++r) {
                const int kvl = 16 * c + lg * 4 + r;
                float v = s[c][r] * 0.125f + (float)bb[r];
                xs[4 * c + r] = (dtile && (kvl > qloc)) ? -1e9f : v;
            }
        }

        float a0 = fmaxf(fmaxf(xs[0], xs[1]),  fmaxf(xs[2], xs[3]));
        float a1 = fmaxf(fmaxf(xs[4], xs[5]),  fmaxf(xs[6], xs[7]));
        float a2 = fmaxf(fmaxf(xs[8], xs[9]),  fmaxf(xs[10], xs[11]));
        float a3 = fmaxf(fmaxf(xs[12], xs[13]), fmaxf(xs[14], xs[15]));
        float pmax = fmaxf(fmaxf(a0, a1), fmaxf(a2, a3));
        pmax = fmaxf(pmax, __shfl_xor(pmax, 16, 64));
        pmax = fmaxf(pmax, __shfl_xor(pmax, 32, 64));

        const float mnew = fmaxf(m_run, pmax);
        const float corr = __expf(m_run - mnew);
        float p[16], ps0 = 0.f, ps1 = 0.f;
#pragma unroll
        for (int j = 0; j < 16; j += 2) {
            p[j]     = __expf(xs[j] - mnew);     ps0 += p[j];
            p[j + 1] = __expf(xs[j + 1] - mnew); ps1 += p[j + 1];
        }
        float ps = ps0 + ps1;
        ps += __shfl_xor(ps, 16, 64);
        ps += __shfl_xor(ps, 32, 64);
        l_run = l_run * corr + ps;
        m_run = mnew;

        float cr[4];
#pragma unroll
        for (int r = 0; r < 4; ++r) cr[r] = __shfl(corr, lg * 4 + r, 64);
#pragma unroll
        for (int nt = 0; nt < 4; ++nt)
#pragma unroll
            for (int r = 0; r < 4; ++r) o[nt][r] *= cr[r];

        char* pw = (char*)Pl[w];
#pragma unroll
        for (int c = 0; c < 4; ++c) {
            bf16x4 pv;
#pragma unroll
            for (int r = 0; r < 4; ++r) pv[r] = (__bf16)p[4 * c + r];
            const int slot = (2 * c + (lg >> 1)) ^ swz;
            *(bf16x4*)(pw + lq * 128 + (slot << 4) + ((lg & 1) << 3)) = pv;
        }

        __builtin_amdgcn_s_setprio(1);
#pragma unroll
        for (int hf = 0; hf < 2; ++hf) {
            const bf16x8 pf = *(const bf16x8*)(pw + lq * 128 + (((hf * 4 + lg) ^ swz) << 4));
#pragma unroll
            for (int nt = 0; nt < 4; ++nt) {
                const bf16x8 vf = *(const bf16x8*)(vb2 + (nt * 16 + lq) * 128
                                                   + (((hf * 4 + lg) ^ swz) << 4));
                o[nt] = MFMA16(pf, vf, o[nt]);
            }
        }
        __builtin_amdgcn_s_setprio(0);

        __syncthreads();
        cur ^= 1;
    }

    const float inv = 1.f / l_run;
    float ir[4];
#pragma unroll
    for (int r = 0; r < 4; ++r) ir[r] = __shfl(inv, lg * 4 + r, 64);
    __hip_bfloat16* op = Out + ((size_t)b * L_ + qc * 64 + w * 16) * D_ + hh * HD_;
#pragma unroll
    for (int nt = 0; nt < 4; ++nt)
#pragma unroll
        for (int r = 0; r < 4; ++r)
            op[(size_t)(lg * 4 + r) * D_ + nt * 16 + lq] = __float2bfloat16(o[nt][r] * ir[r]);
}

// ---------------------------------------------------------------------------
extern "C" void kernel_launch(void* const* d_in, const int* in_sizes, int n_in,
                              void* d_out, int out_size, void* d_ws, size_t ws_size,
                              hipStream_t stream)
{
    const float* x_in  = (const float*)d_in[0];
    const int*   cids  = (const int*)  d_in[1];
    const int*   amask = (const int*)  d_in[2];
    const float* Wq = (const float*)d_in[3];
    const float* bq = (const float*)d_in[4];
    const float* Wk = (const float*)d_in[5];
    const float* bk = (const float*)d_in[6];
    const float* Wv = (const float*)d_in[7];
    const float* bv = (const float*)d_in[8];
    const float* Wo = (const float*)d_in[9];
    const float* bo = (const float*)d_in[10];
    const float* ln1g = (const float*)d_in[11];
    const float* ln1b = (const float*)d_in[12];
    const float* ln2g = (const float*)d_in[13];
    const float* ln2b = (const float*)d_in[14];
    const float* W1 = (const float*)d_in[15];
    const float* b1 = (const float*)d_in[16];
    const float* W2 = (const float*)d_in[17];
    const float* b2 = (const float*)d_in[18];
    const float* cbias = (const float*)d_in[19];
    const float* vbias = (const float*)d_in[20];
    const float* fng = (const float*)d_in[21];
    const float* fnb = (const float*)d_in[22];

    char* w = (char*)d_ws;
    float* x_ws = (float*)w;                 w += (size_t)MTOK * D_ * 4;
    __hip_bfloat16* hbuf = (__hip_bfloat16*)w; w += (size_t)MTOK * D_ * 2;
    __hip_bfloat16* qbuf = (__hip_bfloat16*)w; w += (size_t)MTOK * D_ * 2;
    __hip_bfloat16* kbuf = (__hip_bfloat16*)w; w += (size_t)MTOK * D_ * 2;
    __hip_bfloat16* vtb  = (__hip_bfloat16*)w; w += (size_t)MTOK * D_ * 2;
    __hip_bfloat16* ffb  = (__hip_bfloat16*)w; w += (size_t)MTOK * F_ * 2;
    __hip_bfloat16* WqkvT = (__hip_bfloat16*)w; w += (size_t)NL_ * 3 * D_ * D_ * 2;
    __hip_bfloat16* WoT  = (__hip_bfloat16*)w; w += (size_t)NL_ * D_ * D_ * 2;
    __hip_bfloat16* W1T  = (__hip_bfloat16*)w; w += (size_t)NL_ * D_ * F_ * 2;
    __hip_bfloat16* W2T  = (__hip_bfloat16*)w; w += (size_t)NL_ * D_ * F_ * 2;

    const size_t qkvZ = (size_t)3 * D_ * D_;
    const dim3 tb(32, 8);
    transpose_w<<<dim3(D_/32, D_/32, NL_), tb, 0, stream>>>(Wq, WqkvT,           D_, D_, qkvZ);
    transpose_w<<<dim3(D_/32, D_/32, NL_), tb, 0, stream>>>(Wk, WqkvT + D_*D_,   D_, D_, qkvZ);
    transpose_w<<<dim3(D_/32, D_/32, NL_), tb, 0, stream>>>(Wv, WqkvT + 2*D_*D_, D_, D_, qkvZ);
    transpose_w<<<dim3(D_/32, D_/32, NL_), tb, 0, stream>>>(Wo, WoT, D_, D_, (size_t)D_*D_);
    transpose_w<<<dim3(F_/32, D_/32, NL_), tb, 0, stream>>>(W1, W1T, D_, F_, (size_t)D_*F_);
    transpose_w<<<dim3(D_/32, F_/32, NL_), tb, 0, stream>>>(W2, W2T, F_, D_, (size_t)D_*F_);

    copy_f32x4<<<8192, 256, 0, stream>>>((const float4*)x_in, (float4*)x_ws,
                                         MTOK * D_ / 4);

    const dim3 gQKV(6, 64);    // N=1536, BN=256 -> 384 blocks
    const dim3 gO(4, 64);      // N=512,  BN=128 -> 256 blocks
    const dim3 gW1(8, 64);     // N=2048, BN=256 -> 512 blocks
    const dim3 gW2(4, 64);     // N=512,  BN=128 -> 256 blocks

    for (int i = 0; i < NL_; ++i) {
        ln_kernel<__hip_bfloat16><<<MTOK/4, 256, 0, stream>>>(
            x_ws, ln1g + i * D_, ln1b + i * D_, hbuf);

        gemm_p<4, 4><<<gQKV, 512, 0, stream>>>(hbuf, WqkvT + (size_t)i * qkvZ,
            bq + i*D_, bk + i*D_, bv + i*D_, qbuf, kbuf, vtb, nullptr, 512, D_);

        attn_kernel<<<dim3(B_ * H_, L_/64), 256, 0, stream>>>(
            qbuf, kbuf, vtb, hbuf, cids, amask, cbias, vbias, i);

        gemm_p<1, 2><<<gO, 512, 0, stream>>>(hbuf, WoT + (size_t)i*D_*D_,
            bo + i*D_, nullptr, nullptr, x_ws, nullptr, nullptr, x_ws, D_, D_);

        ln_kernel<__hip_bfloat16><<<MTOK/4, 256, 0, stream>>>(
            x_ws, ln2g + i * D_, ln2b + i * D_, hbuf);

        gemm_p<2, 4><<<gW1, 512, 0, stream>>>(hbuf, W1T + (size_t)i*D_*F_,
            b1 + i*F_, nullptr, nullptr, ffb, nullptr, nullptr, nullptr, F_, D_);

        gemm_p<1, 2><<<gW2, 512, 0, stream>>>(ffb, W2T + (size_t)i*D_*F_,
            b2 + i*D_, nullptr, nullptr, x_ws, nullptr, nullptr, x_ws, D_, F_);
    }

    ln_kernel<float><<<MTOK/4, 256, 0, stream>>>(x_ws, fng, fnb, (float*)d_out);
}

// Round 5
// 1335.104 us; speedup vs baseline: 1.8468x; 1.0515x over previous
//
#include <hip/hip_runtime.h>
#include <hip/hip_bf16.h>

// Problem constants
#define B_   32
#define L_   512
#define D_   512
#define H_   8
#define NL_  6
#define F_   2048
#define C_   9
#define HD_  64
#define MTOK 16384   // B_*L_

typedef __bf16 bf16x8 __attribute__((ext_vector_type(8)));
typedef __bf16 bf16x4 __attribute__((ext_vector_type(4)));
typedef float  f32x4  __attribute__((ext_vector_type(4)));

#define MFMA16(a,b,c) __builtin_amdgcn_mfma_f32_16x16x32_bf16((a),(b),(c),0,0,0)
#define GLD16(g,l) __builtin_amdgcn_global_load_lds( \
    (const __attribute__((address_space(1))) void*)(g), \
    (__attribute__((address_space(3))) void*)(l), 16, 0, 0)

// ---------------------------------------------------------------------------
// Weight transpose + f32->bf16: in [z][K][N] f32 -> out [z-stride zso][N][K]
// ---------------------------------------------------------------------------
__global__ __launch_bounds__(256) void transpose_w(
    const float* __restrict__ in, __hip_bfloat16* __restrict__ out,
    int K, int N, size_t zso)
{
    __shared__ float t[32][33];
    const int z = blockIdx.z;
    const float* src = in + (size_t)z * K * N;
    __hip_bfloat16* dst = out + (size_t)z * zso;
    const int n0 = blockIdx.x * 32, k0 = blockIdx.y * 32;
    const int tx = threadIdx.x, ty = threadIdx.y;   // (32,8)
#pragma unroll
    for (int r = ty; r < 32; r += 8)
        t[r][tx] = src[(size_t)(k0 + r) * N + n0 + tx];
    __syncthreads();
#pragma unroll
    for (int r = ty; r < 32; r += 8)
        dst[(size_t)(n0 + r) * K + k0 + tx] = __float2bfloat16(t[tx][r]);
}

// ---------------------------------------------------------------------------
__global__ void copy_f32x4(const float4* __restrict__ in, float4* __restrict__ out, int n)
{
    int i = blockIdx.x * blockDim.x + threadIdx.x;
    if (i < n) out[i] = in[i];
}

// ---------------------------------------------------------------------------
// LayerNorm: one wave per row (D=512 -> 8 f32/lane). OUT = bf16 or f32.
// ---------------------------------------------------------------------------
template <typename OUT>
__global__ __launch_bounds__(256) void ln_kernel(
    const float* __restrict__ x, const float* __restrict__ g,
    const float* __restrict__ be, OUT* __restrict__ out)
{
    const int row  = blockIdx.x * 4 + (threadIdx.x >> 6);
    const int lane = threadIdx.x & 63;
    const int c0   = lane * 8;
    const float* xr = x + (size_t)row * D_ + c0;
    float4 a = *(const float4*)xr;
    float4 c = *(const float4*)(xr + 4);
    float v[8] = {a.x, a.y, a.z, a.w, c.x, c.y, c.z, c.w};

    float s = 0.f;
#pragma unroll
    for (int j = 0; j < 8; ++j) s += v[j];
#pragma unroll
    for (int o = 1; o < 64; o <<= 1) s += __shfl_xor(s, o, 64);
    const float mu = s * (1.0f / D_);

    float s2 = 0.f;
#pragma unroll
    for (int j = 0; j < 8; ++j) { float d = v[j] - mu; s2 += d * d; }
#pragma unroll
    for (int o = 1; o < 64; o <<= 1) s2 += __shfl_xor(s2, o, 64);
    const float rs = rsqrtf(s2 * (1.0f / D_) + 1e-5f);

    float4 g0 = *(const float4*)(g + c0);
    float4 g1 = *(const float4*)(g + c0 + 4);
    float4 b0 = *(const float4*)(be + c0);
    float4 b1 = *(const float4*)(be + c0 + 4);
    float gg[8] = {g0.x, g0.y, g0.z, g0.w, g1.x, g1.y, g1.z, g1.w};
    float bb[8] = {b0.x, b0.y, b0.z, b0.w, b1.x, b1.y, b1.z, b1.w};

    if constexpr (sizeof(OUT) == 2) {
        bf16x8 o8;
#pragma unroll
        for (int j = 0; j < 8; ++j)
            o8[j] = (__bf16)((v[j] - mu) * rs * gg[j] + bb[j]);
        *(bf16x8*)((__hip_bfloat16*)out + (size_t)row * D_ + c0) = o8;
    } else {
        float* op = (float*)out + (size_t)row * D_ + c0;
        float4 r0, r1;
        r0.x = (v[0]-mu)*rs*gg[0]+bb[0]; r0.y = (v[1]-mu)*rs*gg[1]+bb[1];
        r0.z = (v[2]-mu)*rs*gg[2]+bb[2]; r0.w = (v[3]-mu)*rs*gg[3]+bb[3];
        r1.x = (v[4]-mu)*rs*gg[4]+bb[4]; r1.y = (v[5]-mu)*rs*gg[5]+bb[5];
        r1.z = (v[6]-mu)*rs*gg[6]+bb[6]; r1.w = (v[7]-mu)*rs*gg[7]+bb[7];
        *(float4*)op = r0; *(float4*)(op + 4) = r1;
    }
}

// ---------------------------------------------------------------------------
// gemm_r5: multi-block-overlap GEMM. C[M][N] = A[M][K] @ BT[N][K]^T + bias.
// BK=32, ring-3 LDS (stage tile t+2 into slot freed by this tile's barrier),
// counted vmcnt (never 0 mid-loop), one s_barrier per K-tile, setprio around
// the MFMA cluster. Per-wave 64x64 (FM=FN=4). WN=2 fixed.
//   WM=4: BM=256 BN=128, 8 waves, LDS 72 KiB -> 2 blocks/CU  [QKV, W1]
//   WM=2: BM=128 BN=128, 4 waves, LDS 48 KiB -> 3 blocks/CU  [O, W2]
// LDS chunk swizzle: stored chunk c holds global chunk c^((row>>1)&3)
// (2-way max aliasing = free); same involution on read.
// EPI: 1 = f32 residual add (out0==Res); 2 = exact GELU -> bf16;
//      4 = fused QKV epilogue (out0=q, out1=k, out2=VT[b][d][l]).
// ---------------------------------------------------------------------------
template <int EPI, int WM>
__global__ __launch_bounds__(WM * 128, (WM == 4) ? 4 : 3) void gemm_r5(
    const __hip_bfloat16* __restrict__ A,
    const __hip_bfloat16* __restrict__ BT,
    const float* __restrict__ bias0, const float* __restrict__ bias1,
    const float* __restrict__ bias2,
    void* __restrict__ out0, void* __restrict__ out1, void* __restrict__ out2,
    const float* __restrict__ Res, int Ndim, int K)
{
    constexpr int THREADS = WM * 128;
    constexpr int BM = WM * 64;
    __shared__ __align__(16) __hip_bfloat16 As[3][BM * 32];
    __shared__ __align__(16) __hip_bfloat16 Bs[3][128 * 32];

    const int tid = threadIdx.x;
    const int w = tid >> 6, lane = tid & 63;
    const int lq = lane & 15, lg = lane >> 4;
    const int wm = w >> 1, wn = w & 1;
    const int RB = wm * 64, CB = wn * 64;

    // T1: bijective XCD swizzle (nwg % 8 == 0 for all launches here)
    const int gX = gridDim.x;
    const int nwg = gX * gridDim.y;
    int flat = blockIdx.y * gX + blockIdx.x;
    {
        const int qq = nwg >> 3, rr = nwg & 7;
        const int xcd = flat & 7, off = flat >> 3;
        flat = (xcd < rr ? xcd * (qq + 1) : rr * (qq + 1) + (xcd - rr) * qq) + off;
    }
    const int bx = flat % gX, by = flat / gX;
    const int m0 = by * BM, n0 = bx * 128;

    // ---- staging geometry (pre-swizzled source, linear LDS dest) ----
    const int rc = tid >> 2;                       // row within operand tile
    const int sc = ((tid & 3) ^ ((rc >> 1) & 3)) * 8;
    const __hip_bfloat16* gA0 = A  + (size_t)(m0 + rc) * K + sc;
    const __hip_bfloat16* gB0 = BT + (size_t)(n0 + rc) * K + sc;

    auto STAGE = [&](int tt) {
        const size_t ko = (size_t)tt * 32;
        const int sl = tt % 3;
        char* ab = (char*)As[sl] + w * 1024;
        GLD16(gA0 + ko, ab);
        GLD16(gA0 + (size_t)(THREADS / 4) * K + ko, ab + THREADS * 16);
        char* bb = (char*)Bs[sl] + w * 1024;
        GLD16(gB0 + ko, bb);
        if constexpr (WM == 2)
            GLD16(gB0 + (size_t)64 * K + ko, bb + 4096);
    };

    // ---- fragment read offsets (bytes), chunk-swizzled ----
    const int rsw = (lq >> 1) & 3;
    const int aoff = (RB + lq) * 64 + ((lg ^ rsw) << 4);
    const int boff = (CB + lq) * 64 + ((lg ^ rsw) << 4);

    f32x4 acc[4][4] = {};
    const int NTt = K >> 5;

    STAGE(0); STAGE(1);

    for (int t = 0; t < NTt; ++t) {
        if (t + 1 < NTt) {
            if constexpr (WM == 4) asm volatile("s_waitcnt vmcnt(3)" ::: "memory");
            else                   asm volatile("s_waitcnt vmcnt(4)" ::: "memory");
        } else {
            asm volatile("s_waitcnt vmcnt(0)" ::: "memory");
        }
        __builtin_amdgcn_s_barrier();
        __builtin_amdgcn_sched_barrier(0);

        const char* ca = (const char*)As[t % 3];
        const char* cb = (const char*)Bs[t % 3];
        bf16x8 af[4], bf[4];
#pragma unroll
        for (int fm = 0; fm < 4; ++fm) af[fm] = *(const bf16x8*)(ca + aoff + fm * 1024);
#pragma unroll
        for (int fn = 0; fn < 4; ++fn) bf[fn] = *(const bf16x8*)(cb + boff + fn * 1024);

        if (t + 2 < NTt) STAGE(t + 2);   // slot (t+2)%3: freed by this barrier

        __builtin_amdgcn_s_setprio(1);
#pragma unroll
        for (int fm = 0; fm < 4; ++fm)
#pragma unroll
            for (int fn = 0; fn < 4; ++fn)
                acc[fm][fn] = MFMA16(af[fm], bf[fn], acc[fm][fn]);
        __builtin_amdgcn_s_setprio(0);
    }

    // ---- epilogue ----
    if constexpr (EPI == 4) {
        const int sec = n0 >> 9;                 // 0=q, 1=k, 2=v
        const int nb = (n0 & 511) + CB;
        const float* bp = sec == 0 ? bias0 : (sec == 1 ? bias1 : bias2);
        float bcol[4];
#pragma unroll
        for (int fn = 0; fn < 4; ++fn) bcol[fn] = bp[nb + fn * 16 + lq];
        if (sec < 2) {
            __hip_bfloat16* op = (__hip_bfloat16*)(sec == 0 ? out0 : out1);
#pragma unroll
            for (int fm = 0; fm < 4; ++fm)
#pragma unroll
                for (int fn = 0; fn < 4; ++fn)
#pragma unroll
                    for (int r = 0; r < 4; ++r) {
                        const int m = m0 + RB + fm * 16 + lg * 4 + r;
                        op[(size_t)m * 512 + nb + fn * 16 + lq] =
                            __float2bfloat16(acc[fm][fn][r] + bcol[fn]);
                    }
        } else {
            __hip_bfloat16* vp = (__hip_bfloat16*)out2;
            const int bb = m0 >> 9;
            const int l0 = (m0 & 511) + RB + lg * 4;
#pragma unroll
            for (int fm = 0; fm < 4; ++fm)
#pragma unroll
                for (int fn = 0; fn < 4; ++fn) {
                    bf16x4 pv;
#pragma unroll
                    for (int r = 0; r < 4; ++r)
                        pv[r] = (__bf16)(acc[fm][fn][r] + bcol[fn]);
                    *(bf16x4*)(vp + ((size_t)(bb * 512 + nb + fn * 16 + lq)) * 512
                               + l0 + fm * 16) = pv;
                }
        }
    } else {
        float bcol[4];
#pragma unroll
        for (int fn = 0; fn < 4; ++fn) bcol[fn] = bias0[n0 + CB + fn * 16 + lq];
#pragma unroll
        for (int fm = 0; fm < 4; ++fm)
#pragma unroll
            for (int fn = 0; fn < 4; ++fn) {
                const int n = n0 + CB + fn * 16 + lq;
#pragma unroll
                for (int r = 0; r < 4; ++r) {
                    const int m = m0 + RB + fm * 16 + lg * 4 + r;
                    float v = acc[fm][fn][r] + bcol[fn];
                    if constexpr (EPI == 1) {
                        float* Co = (float*)out0;
                        const size_t idx = (size_t)m * Ndim + n;
                        Co[idx] = Res[idx] + v;
                    } else {  // EPI == 2
                        float gl = 0.5f * v * (1.0f + erff(v * 0.70710678118654752f));
                        ((__hip_bfloat16*)out0)[(size_t)m * Ndim + n] = __float2bfloat16(gl);
                    }
                }
            }
    }
}

// ---------------------------------------------------------------------------
// Flash attention: 4 waves/block, 64 q-rows/block, KV tiles of 64,
// K/V double-buffered in LDS (pre-swizzled global_load_lds source).
// ---------------------------------------------------------------------------
__global__ __launch_bounds__(256) void attn_kernel(
    const __hip_bfloat16* __restrict__ Q, const __hip_bfloat16* __restrict__ K,
    const __hip_bfloat16* __restrict__ VT, __hip_bfloat16* __restrict__ Out,
    const int* __restrict__ case_ids, const int* __restrict__ amask,
    const float* __restrict__ case_bias, const float* __restrict__ verb_bias,
    int layer)
{
    __shared__ __align__(16) __bf16 Ks[2][64 * 64];
    __shared__ __align__(16) __bf16 Vs[2][64 * 64];
    __shared__ __align__(16) __bf16 Pl[4][16 * 64];
    __shared__ __bf16 Bia[9][520];

    const int bh = blockIdx.x;
    const int b = bh >> 3, hh = bh & 7;
    const int qc = blockIdx.y;
    const int t = threadIdx.x;
    const int w = t >> 6, lane = t & 63;
    const int lq = lane & 15, lg = lane >> 4;
    const int swz = lq & 7;

    const int rA = w * 16 + (lane >> 3);
    const int swsrc = ((lane & 7) ^ (lane >> 3)) << 4;
    const __hip_bfloat16* kg0 = K  + ((size_t)b * L_ + rA) * D_ + hh * HD_;
    const __hip_bfloat16* vg0 = VT + ((size_t)b * D_ + hh * HD_ + rA) * L_;

    auto stage = [&](int buf, int kv0) {
        const char* gk = (const char*)(kg0 + (size_t)kv0 * D_) + swsrc;
        GLD16(gk,                      (char*)Ks[buf] + w * 2048);
        GLD16(gk + (size_t)8 * D_ * 2, (char*)Ks[buf] + w * 2048 + 1024);
        const char* gv = (const char*)(vg0 + kv0) + swsrc;
        GLD16(gv,                      (char*)Vs[buf] + w * 2048);
        GLD16(gv + (size_t)8 * L_ * 2, (char*)Vs[buf] + w * 2048 + 1024);
    };

    stage(0, 0);

    const float vb = verb_bias[layer * H_ + hh];
    const float* cb = case_bias + ((size_t)layer * H_ + hh) * (C_ * C_);
    for (int idx = t; idx < 9 * 512; idx += 256) {
        const int ci = idx >> 9, kv = idx & 511;
        const int cj = case_ids[b * L_ + kv];
        Bia[ci][kv] = (__bf16)(cb[ci * C_ + cj] + (cj == 8 ? vb : 0.f)
                               - 10000.f * (1.f - (float)amask[b * L_ + kv]));
    }
    __syncthreads();

    const int qloc = w * 16 + lq;
    const int qrow = qc * 64 + qloc;
    const int ci_q = case_ids[b * L_ + qrow];
    const __hip_bfloat16* qp = Q + ((size_t)b * L_ + qrow) * D_ + hh * HD_;
    const bf16x8 qf0 = *(const bf16x8*)(qp + lg * 8);
    const bf16x8 qf1 = *(const bf16x8*)(qp + 32 + lg * 8);

    float m_run = -1e30f, l_run = 0.f;
    f32x4 o[4] = {};
    const int ntiles = qc + 1;
    int cur = 0;

    for (int kt = 0; kt < ntiles; ++kt) {
        if (kt + 1 < ntiles) stage(cur ^ 1, (kt + 1) * 64);

        const char* kb  = (const char*)Ks[cur];
        const char* vb2 = (const char*)Vs[cur];

        f32x4 s[4] = {};
        __builtin_amdgcn_s_setprio(1);
#pragma unroll
        for (int c = 0; c < 4; ++c) {
            const bf16x8 ka = *(const bf16x8*)(kb + (16 * c + lq) * 128 + ((lg ^ swz) << 4));
            s[c] = MFMA16(ka, qf0, s[c]);
            const bf16x8 kc = *(const bf16x8*)(kb + (16 * c + lq) * 128 + (((4 + lg) ^ swz) << 4));
            s[c] = MFMA16(kc, qf1, s[c]);
        }
        __builtin_amdgcn_s_setprio(0);

        const __bf16* brow = &Bia[ci_q][kt * 64];
        const bool dtile = (kt == qc);
        float xs[16];
#pragma unroll
        for (int c = 0; c < 4; ++c) {
            const bf16x4 bb = *(const bf16x4*)(brow + 16 * c + lg * 4);
#pragma unroll
            for (int r = 0; r < 4; ++r) {
                const int kvl = 16 * c + lg * 4 + r;
                float v = s[c][r] * 0.125f + (float)bb[r];
                xs[4 * c + r] = (dtile && (kvl > qloc)) ? -1e9f : v;
            }
        }

        float a0 = fmaxf(fmaxf(xs[0], xs[1]),  fmaxf(xs[2], xs[3]));
        float a1 = fmaxf(fmaxf(xs[4], xs[5]),  fmaxf(xs[6], xs[7]));
        float a2 = fmaxf(fmaxf(xs[8], xs[9]),  fmaxf(xs[10], xs[11]));
        float a3 = fmaxf(fmaxf(xs[12], xs[13]), fmaxf(xs[14], xs[15]));
        float pmax = fmaxf(fmaxf(a0, a1), fmaxf(a2, a3));
        pmax = fmaxf(pmax, __shfl_xor(pmax, 16, 64));
        pmax = fmaxf(pmax, __shfl_xor(pmax, 32, 64));

        const float mnew = fmaxf(m_run, pmax);
        const float corr = __expf(m_run - mnew);
        float p[16], ps0 = 0.f, ps1 = 0.f;
#pragma unroll
        for (int j = 0; j < 16; j += 2) {
            p[j]     = __expf(xs[j] - mnew);     ps0 += p[j];
            p[j + 1] = __expf(xs[j + 1] - mnew); ps1 += p[j + 1];
        }
        float ps = ps0 + ps1;
        ps += __shfl_xor(ps, 16, 64);
        ps += __shfl_xor(ps, 32, 64);
        l_run = l_run * corr + ps;
        m_run = mnew;

        float cr[4];
#pragma unroll
        for (int r = 0; r < 4; ++r) cr[r] = __shfl(corr, lg * 4 + r, 64);
#pragma unroll
        for (int nt = 0; nt < 4; ++nt)
#pragma unroll
            for (int r = 0; r < 4; ++r) o[nt][r] *= cr[r];

        char* pw = (char*)Pl[w];
#pragma unroll
        for (int c = 0; c < 4; ++c) {
            bf16x4 pv;
#pragma unroll
            for (int r = 0; r < 4; ++r) pv[r] = (__bf16)p[4 * c + r];
            const int slot = (2 * c + (lg >> 1)) ^ swz;
            *(bf16x4*)(pw + lq * 128 + (slot << 4) + ((lg & 1) << 3)) = pv;
        }

        __builtin_amdgcn_s_setprio(1);
#pragma unroll
        for (int hf = 0; hf < 2; ++hf) {
            const bf16x8 pf = *(const bf16x8*)(pw + lq * 128 + (((hf * 4 + lg) ^ swz) << 4));
#pragma unroll
            for (int nt = 0; nt < 4; ++nt) {
                const bf16x8 vf = *(const bf16x8*)(vb2 + (nt * 16 + lq) * 128
                                                   + (((hf * 4 + lg) ^ swz) << 4));
                o[nt] = MFMA16(pf, vf, o[nt]);
            }
        }
        __builtin_amdgcn_s_setprio(0);

        __syncthreads();
        cur ^= 1;
    }

    const float inv = 1.f / l_run;
    float ir[4];
#pragma unroll
    for (int r = 0; r < 4; ++r) ir[r] = __shfl(inv, lg * 4 + r, 64);
    __hip_bfloat16* op = Out + ((size_t)b * L_ + qc * 64 + w * 16) * D_ + hh * HD_;
#pragma unroll
    for (int nt = 0; nt < 4; ++nt)
#pragma unroll
        for (int r = 0; r < 4; ++r)
            op[(size_t)(lg * 4 + r) * D_ + nt * 16 + lq] = __float2bfloat16(o[nt][r] * ir[r]);
}

// ---------------------------------------------------------------------------
extern "C" void kernel_launch(void* const* d_in, const int* in_sizes, int n_in,
                              void* d_out, int out_size, void* d_ws, size_t ws_size,
                              hipStream_t stream)
{
    const float* x_in  = (const float*)d_in[0];
    const int*   cids  = (const int*)  d_in[1];
    const int*   amask = (const int*)  d_in[2];
    const float* Wq = (const float*)d_in[3];
    const float* bq = (const float*)d_in[4];
    const float* Wk = (const float*)d_in[5];
    const float* bk = (const float*)d_in[6];
    const float* Wv = (const float*)d_in[7];
    const float* bv = (const float*)d_in[8];
    const float* Wo = (const float*)d_in[9];
    const float* bo = (const float*)d_in[10];
    const float* ln1g = (const float*)d_in[11];
    const float* ln1b = (const float*)d_in[12];
    const float* ln2g = (const float*)d_in[13];
    const float* ln2b = (const float*)d_in[14];
    const float* W1 = (const float*)d_in[15];
    const float* b1 = (const float*)d_in[16];
    const float* W2 = (const float*)d_in[17];
    const float* b2 = (const float*)d_in[18];
    const float* cbias = (const float*)d_in[19];
    const float* vbias = (const float*)d_in[20];
    const float* fng = (const float*)d_in[21];
    const float* fnb = (const float*)d_in[22];

    char* w = (char*)d_ws;
    float* x_ws = (float*)w;                 w += (size_t)MTOK * D_ * 4;
    __hip_bfloat16* hbuf = (__hip_bfloat16*)w; w += (size_t)MTOK * D_ * 2;
    __hip_bfloat16* qbuf = (__hip_bfloat16*)w; w += (size_t)MTOK * D_ * 2;
    __hip_bfloat16* kbuf = (__hip_bfloat16*)w; w += (size_t)MTOK * D_ * 2;
    __hip_bfloat16* vtb  = (__hip_bfloat16*)w; w += (size_t)MTOK * D_ * 2;
    __hip_bfloat16* ffb  = (__hip_bfloat16*)w; w += (size_t)MTOK * F_ * 2;
    __hip_bfloat16* WqkvT = (__hip_bfloat16*)w; w += (size_t)NL_ * 3 * D_ * D_ * 2;
    __hip_bfloat16* WoT  = (__hip_bfloat16*)w; w += (size_t)NL_ * D_ * D_ * 2;
    __hip_bfloat16* W1T  = (__hip_bfloat16*)w; w += (size_t)NL_ * D_ * F_ * 2;
    __hip_bfloat16* W2T  = (__hip_bfloat16*)w; w += (size_t)NL_ * D_ * F_ * 2;

    const size_t qkvZ = (size_t)3 * D_ * D_;
    const dim3 tb(32, 8);
    transpose_w<<<dim3(D_/32, D_/32, NL_), tb, 0, stream>>>(Wq, WqkvT,           D_, D_, qkvZ);
    transpose_w<<<dim3(D_/32, D_/32, NL_), tb, 0, stream>>>(Wk, WqkvT + D_*D_,   D_, D_, qkvZ);
    transpose_w<<<dim3(D_/32, D_/32, NL_), tb, 0, stream>>>(Wv, WqkvT + 2*D_*D_, D_, D_, qkvZ);
    transpose_w<<<dim3(D_/32, D_/32, NL_), tb, 0, stream>>>(Wo, WoT, D_, D_, (size_t)D_*D_);
    transpose_w<<<dim3(F_/32, D_/32, NL_), tb, 0, stream>>>(W1, W1T, D_, F_, (size_t)D_*F_);
    transpose_w<<<dim3(D_/32, F_/32, NL_), tb, 0, stream>>>(W2, W2T, F_, D_, (size_t)D_*F_);

    copy_f32x4<<<8192, 256, 0, stream>>>((const float4*)x_in, (float4*)x_ws,
                                         MTOK * D_ / 4);

    const dim3 gQKV(12, 64);   // BM=256: 64 m-blocks x 12 n-blocks = 768
    const dim3 gO(4, 128);     // BM=128: 128 x 4 = 512
    const dim3 gW1(16, 64);    // BM=256: 64 x 16 = 1024
    const dim3 gW2(4, 128);    // BM=128: 128 x 4 = 512

    for (int i = 0; i < NL_; ++i) {
        ln_kernel<__hip_bfloat16><<<MTOK/4, 256, 0, stream>>>(
            x_ws, ln1g + i * D_, ln1b + i * D_, hbuf);

        gemm_r5<4, 4><<<gQKV, 512, 0, stream>>>(hbuf, WqkvT + (size_t)i * qkvZ,
            bq + i*D_, bk + i*D_, bv + i*D_, qbuf, kbuf, vtb, nullptr, 512, D_);

        attn_kernel<<<dim3(B_ * H_, L_/64), 256, 0, stream>>>(
            qbuf, kbuf, vtb, hbuf, cids, amask, cbias, vbias, i);

        gemm_r5<1, 2><<<gO, 256, 0, stream>>>(hbuf, WoT + (size_t)i*D_*D_,
            bo + i*D_, nullptr, nullptr, x_ws, nullptr, nullptr, x_ws, D_, D_);

        ln_kernel<__hip_bfloat16><<<MTOK/4, 256, 0, stream>>>(
            x_ws, ln2g + i * D_, ln2b + i * D_, hbuf);

        gemm_r5<2, 4><<<gW1, 512, 0, stream>>>(hbuf, W1T + (size_t)i*D_*F_,
            b1 + i*F_, nullptr, nullptr, ffb, nullptr, nullptr, nullptr, F_, D_);

        gemm_r5<1, 2><<<gW2, 256, 0, stream>>>(ffb, W2T + (size_t)i*D_*F_,
            b2 + i*D_, nullptr, nullptr, x_ws, nullptr, nullptr, x_ws, D_, F_);
    }

    ln_kernel<float><<<MTOK/4, 256, 0, stream>>>(x_ws, fng, fnb, (float*)d_out);
}

// Round 6
// 1325.643 us; speedup vs baseline: 1.8600x; 1.0071x over previous
//
#include <hip/hip_runtime.h>
#include <hip/hip_bf16.h>

// Problem constants
#define B_   32
#define L_   512
#define D_   512
#define H_   8
#define NL_  6
#define F_   2048
#define C_   9
#define HD_  64
#define MTOK 16384   // B_*L_

typedef __bf16 bf16x8 __attribute__((ext_vector_type(8)));
typedef __bf16 bf16x4 __attribute__((ext_vector_type(4)));
typedef float  f32x4  __attribute__((ext_vector_type(4)));

#define MFMA16(a,b,c) __builtin_amdgcn_mfma_f32_16x16x32_bf16((a),(b),(c),0,0,0)
#define GLD16(g,l) __builtin_amdgcn_global_load_lds( \
    (const __attribute__((address_space(1))) void*)(g), \
    (__attribute__((address_space(3))) void*)(l), 16, 0, 0)

// ---------------------------------------------------------------------------
// Weight transpose + f32->bf16: in [z][K][N] f32 -> out [z-stride zso][N][K]
// ---------------------------------------------------------------------------
__global__ __launch_bounds__(256) void transpose_w(
    const float* __restrict__ in, __hip_bfloat16* __restrict__ out,
    int K, int N, size_t zso)
{
    __shared__ float t[32][33];
    const int z = blockIdx.z;
    const float* src = in + (size_t)z * K * N;
    __hip_bfloat16* dst = out + (size_t)z * zso;
    const int n0 = blockIdx.x * 32, k0 = blockIdx.y * 32;
    const int tx = threadIdx.x, ty = threadIdx.y;   // (32,8)
#pragma unroll
    for (int r = ty; r < 32; r += 8)
        t[r][tx] = src[(size_t)(k0 + r) * N + n0 + tx];
    __syncthreads();
#pragma unroll
    for (int r = ty; r < 32; r += 8)
        dst[(size_t)(n0 + r) * K + k0 + tx] = __float2bfloat16(t[tx][r]);
}

// ---------------------------------------------------------------------------
__global__ void copy_f32x4(const float4* __restrict__ in, float4* __restrict__ out, int n)
{
    int i = blockIdx.x * blockDim.x + threadIdx.x;
    if (i < n) out[i] = in[i];
}

// ---------------------------------------------------------------------------
// LayerNorm: one wave per row (D=512 -> 8 f32/lane). OUT = bf16 or f32.
// ---------------------------------------------------------------------------
template <typename OUT>
__global__ __launch_bounds__(256) void ln_kernel(
    const float* __restrict__ x, const float* __restrict__ g,
    const float* __restrict__ be, OUT* __restrict__ out)
{
    const int row  = blockIdx.x * 4 + (threadIdx.x >> 6);
    const int lane = threadIdx.x & 63;
    const int c0   = lane * 8;
    const float* xr = x + (size_t)row * D_ + c0;
    float4 a = *(const float4*)xr;
    float4 c = *(const float4*)(xr + 4);
    float v[8] = {a.x, a.y, a.z, a.w, c.x, c.y, c.z, c.w};

    float s = 0.f;
#pragma unroll
    for (int j = 0; j < 8; ++j) s += v[j];
#pragma unroll
    for (int o = 1; o < 64; o <<= 1) s += __shfl_xor(s, o, 64);
    const float mu = s * (1.0f / D_);

    float s2 = 0.f;
#pragma unroll
    for (int j = 0; j < 8; ++j) { float d = v[j] - mu; s2 += d * d; }
#pragma unroll
    for (int o = 1; o < 64; o <<= 1) s2 += __shfl_xor(s2, o, 64);
    const float rs = rsqrtf(s2 * (1.0f / D_) + 1e-5f);

    float4 g0 = *(const float4*)(g + c0);
    float4 g1 = *(const float4*)(g + c0 + 4);
    float4 b0 = *(const float4*)(be + c0);
    float4 b1 = *(const float4*)(be + c0 + 4);
    float gg[8] = {g0.x, g0.y, g0.z, g0.w, g1.x, g1.y, g1.z, g1.w};
    float bb[8] = {b0.x, b0.y, b0.z, b0.w, b1.x, b1.y, b1.z, b1.w};

    if constexpr (sizeof(OUT) == 2) {
        bf16x8 o8;
#pragma unroll
        for (int j = 0; j < 8; ++j)
            o8[j] = (__bf16)((v[j] - mu) * rs * gg[j] + bb[j]);
        *(bf16x8*)((__hip_bfloat16*)out + (size_t)row * D_ + c0) = o8;
    } else {
        float* op = (float*)out + (size_t)row * D_ + c0;
        float4 r0, r1;
        r0.x = (v[0]-mu)*rs*gg[0]+bb[0]; r0.y = (v[1]-mu)*rs*gg[1]+bb[1];
        r0.z = (v[2]-mu)*rs*gg[2]+bb[2]; r0.w = (v[3]-mu)*rs*gg[3]+bb[3];
        r1.x = (v[4]-mu)*rs*gg[4]+bb[4]; r1.y = (v[5]-mu)*rs*gg[5]+bb[5];
        r1.z = (v[6]-mu)*rs*gg[6]+bb[6]; r1.w = (v[7]-mu)*rs*gg[7]+bb[7];
        *(float4*)op = r0; *(float4*)(op + 4) = r1;
    }
}

// fast branchless tanh-form GELU (max abs err ~2.5e-4 vs exact erf form)
__device__ __forceinline__ float gelu_tanh(float v)
{
    const float t2 = v * v;
    const float u  = v * (0.7978845608028654f + 0.0356774081363001f * t2);
    const float a  = __builtin_fabsf(u);
    const float e  = __expf(-2.0f * a);
    const float r  = __builtin_amdgcn_rcpf(1.0f + e);
    const float th = (1.0f - e) * r;               // |tanh(u)|
    return 0.5f * v + 0.5f * __builtin_fabsf(v) * th;
}

// ---------------------------------------------------------------------------
// gemm_r5: multi-block-overlap GEMM. C[M][N] = A[M][K] @ BT[N][K]^T + bias.
// BK=32, ring-3 LDS, counted vmcnt (never 0 mid-loop), one s_barrier per
// K-tile, setprio around the MFMA cluster. Per-wave 64x64 (FM=FN=4).
//   WM=4: BM=256 BN=128, 8 waves, LDS 72 KiB  [QKV, W1]
//   WM=2: BM=128 BN=128, 4 waves, LDS 48 KiB  [O, W2]
// EPI: 1 = f32 residual add (out0==Res); 2 = tanh-GELU -> bf16;
//      4 = fused QKV epilogue (out0=q, out1=k, out2=VT[b][d][l]).
// ---------------------------------------------------------------------------
template <int EPI, int WM>
__global__ __launch_bounds__(WM * 128, (WM == 4) ? 4 : 3) void gemm_r5(
    const __hip_bfloat16* __restrict__ A,
    const __hip_bfloat16* __restrict__ BT,
    const float* __restrict__ bias0, const float* __restrict__ bias1,
    const float* __restrict__ bias2,
    void* __restrict__ out0, void* __restrict__ out1, void* __restrict__ out2,
    const float* __restrict__ Res, int Ndim, int K)
{
    constexpr int THREADS = WM * 128;
    constexpr int BM = WM * 64;
    __shared__ __align__(16) __hip_bfloat16 As[3][BM * 32];
    __shared__ __align__(16) __hip_bfloat16 Bs[3][128 * 32];

    const int tid = threadIdx.x;
    const int w = tid >> 6, lane = tid & 63;
    const int lq = lane & 15, lg = lane >> 4;
    const int wm = w >> 1, wn = w & 1;
    const int RB = wm * 64, CB = wn * 64;

    // T1: bijective XCD swizzle (nwg % 8 == 0 for all launches here)
    const int gX = gridDim.x;
    const int nwg = gX * gridDim.y;
    int flat = blockIdx.y * gX + blockIdx.x;
    {
        const int qq = nwg >> 3, rr = nwg & 7;
        const int xcd = flat & 7, off = flat >> 3;
        flat = (xcd < rr ? xcd * (qq + 1) : rr * (qq + 1) + (xcd - rr) * qq) + off;
    }
    const int bx = flat % gX, by = flat / gX;
    const int m0 = by * BM, n0 = bx * 128;

    // ---- staging geometry (pre-swizzled source, linear LDS dest) ----
    const int rc = tid >> 2;                       // row within operand tile
    const int sc = ((tid & 3) ^ ((rc >> 1) & 3)) * 8;
    const __hip_bfloat16* gA0 = A  + (size_t)(m0 + rc) * K + sc;
    const __hip_bfloat16* gB0 = BT + (size_t)(n0 + rc) * K + sc;

    auto STAGE = [&](int tt) {
        const size_t ko = (size_t)tt * 32;
        const int sl = tt % 3;
        char* ab = (char*)As[sl] + w * 1024;
        GLD16(gA0 + ko, ab);
        GLD16(gA0 + (size_t)(THREADS / 4) * K + ko, ab + THREADS * 16);
        char* bb = (char*)Bs[sl] + w * 1024;
        GLD16(gB0 + ko, bb);
        if constexpr (WM == 2)
            GLD16(gB0 + (size_t)64 * K + ko, bb + 4096);
    };

    // ---- fragment read offsets (bytes), chunk-swizzled ----
    const int rsw = (lq >> 1) & 3;
    const int aoff = (RB + lq) * 64 + ((lg ^ rsw) << 4);
    const int boff = (CB + lq) * 64 + ((lg ^ rsw) << 4);

    f32x4 acc[4][4] = {};
    const int NTt = K >> 5;

    STAGE(0); STAGE(1);

    for (int t = 0; t < NTt; ++t) {
        if (t + 1 < NTt) {
            if constexpr (WM == 4) asm volatile("s_waitcnt vmcnt(3)" ::: "memory");
            else                   asm volatile("s_waitcnt vmcnt(4)" ::: "memory");
        } else {
            asm volatile("s_waitcnt vmcnt(0)" ::: "memory");
        }
        __builtin_amdgcn_s_barrier();
        __builtin_amdgcn_sched_barrier(0);

        const char* ca = (const char*)As[t % 3];
        const char* cb = (const char*)Bs[t % 3];
        bf16x8 af[4], bf[4];
#pragma unroll
        for (int fm = 0; fm < 4; ++fm) af[fm] = *(const bf16x8*)(ca + aoff + fm * 1024);
#pragma unroll
        for (int fn = 0; fn < 4; ++fn) bf[fn] = *(const bf16x8*)(cb + boff + fn * 1024);

        if (t + 2 < NTt) STAGE(t + 2);   // slot (t+2)%3: freed by this barrier

        __builtin_amdgcn_s_setprio(1);
#pragma unroll
        for (int fm = 0; fm < 4; ++fm)
#pragma unroll
            for (int fn = 0; fn < 4; ++fn)
                acc[fm][fn] = MFMA16(af[fm], bf[fn], acc[fm][fn]);
        __builtin_amdgcn_s_setprio(0);
    }

    // ---- epilogue ----
    if constexpr (EPI == 4) {
        const int sec = n0 >> 9;                 // 0=q, 1=k, 2=v
        const int nb = (n0 & 511) + CB;
        const float* bp = sec == 0 ? bias0 : (sec == 1 ? bias1 : bias2);
        float bcol[4];
#pragma unroll
        for (int fn = 0; fn < 4; ++fn) bcol[fn] = bp[nb + fn * 16 + lq];
        if (sec < 2) {
            __hip_bfloat16* op = (__hip_bfloat16*)(sec == 0 ? out0 : out1);
#pragma unroll
            for (int fm = 0; fm < 4; ++fm)
#pragma unroll
                for (int fn = 0; fn < 4; ++fn)
#pragma unroll
                    for (int r = 0; r < 4; ++r) {
                        const int m = m0 + RB + fm * 16 + lg * 4 + r;
                        op[(size_t)m * 512 + nb + fn * 16 + lq] =
                            __float2bfloat16(acc[fm][fn][r] + bcol[fn]);
                    }
        } else {
            __hip_bfloat16* vp = (__hip_bfloat16*)out2;
            const int bb = m0 >> 9;
            const int l0 = (m0 & 511) + RB + lg * 4;
#pragma unroll
            for (int fm = 0; fm < 4; ++fm)
#pragma unroll
                for (int fn = 0; fn < 4; ++fn) {
                    bf16x4 pv;
#pragma unroll
                    for (int r = 0; r < 4; ++r)
                        pv[r] = (__bf16)(acc[fm][fn][r] + bcol[fn]);
                    *(bf16x4*)(vp + ((size_t)(bb * 512 + nb + fn * 16 + lq)) * 512
                               + l0 + fm * 16) = pv;
                }
        }
    } else {
        float bcol[4];
#pragma unroll
        for (int fn = 0; fn < 4; ++fn) bcol[fn] = bias0[n0 + CB + fn * 16 + lq];
#pragma unroll
        for (int fm = 0; fm < 4; ++fm)
#pragma unroll
            for (int fn = 0; fn < 4; ++fn) {
                const int n = n0 + CB + fn * 16 + lq;
#pragma unroll
                for (int r = 0; r < 4; ++r) {
                    const int m = m0 + RB + fm * 16 + lg * 4 + r;
                    float v = acc[fm][fn][r] + bcol[fn];
                    if constexpr (EPI == 1) {
                        float* Co = (float*)out0;
                        const size_t idx = (size_t)m * Ndim + n;
                        Co[idx] = Res[idx] + v;
                    } else {  // EPI == 2: tanh-GELU
                        ((__hip_bfloat16*)out0)[(size_t)m * Ndim + n] =
                            __float2bfloat16(gelu_tanh(v));
                    }
                }
            }
    }
}

// ---------------------------------------------------------------------------
// Flash attention: 4 waves/block, 64 q-rows/block, KV tiles of 64,
// K/V double-buffered in LDS; raw s_barrier + counted vmcnt (loads ride
// across barriers; no full drain per tile).
// ---------------------------------------------------------------------------
__global__ __launch_bounds__(256) void attn_kernel(
    const __hip_bfloat16* __restrict__ Q, const __hip_bfloat16* __restrict__ K,
    const __hip_bfloat16* __restrict__ VT, __hip_bfloat16* __restrict__ Out,
    const int* __restrict__ case_ids, const int* __restrict__ amask,
    const float* __restrict__ case_bias, const float* __restrict__ verb_bias,
    int layer)
{
    __shared__ __align__(16) __bf16 Ks[2][64 * 64];
    __shared__ __align__(16) __bf16 Vs[2][64 * 64];
    __shared__ __align__(16) __bf16 Pl[4][16 * 64];
    __shared__ __bf16 Bia[9][520];

    const int bh = blockIdx.x;
    const int b = bh >> 3, hh = bh & 7;
    const int qc = blockIdx.y;
    const int t = threadIdx.x;
    const int w = t >> 6, lane = t & 63;
    const int lq = lane & 15, lg = lane >> 4;
    const int swz = lq & 7;

    const int rA = w * 16 + (lane >> 3);
    const int swsrc = ((lane & 7) ^ (lane >> 3)) << 4;
    const __hip_bfloat16* kg0 = K  + ((size_t)b * L_ + rA) * D_ + hh * HD_;
    const __hip_bfloat16* vg0 = VT + ((size_t)b * D_ + hh * HD_ + rA) * L_;

    auto stage = [&](int buf, int kv0) {
        const char* gk = (const char*)(kg0 + (size_t)kv0 * D_) + swsrc;
        GLD16(gk,                      (char*)Ks[buf] + w * 2048);
        GLD16(gk + (size_t)8 * D_ * 2, (char*)Ks[buf] + w * 2048 + 1024);
        const char* gv = (const char*)(vg0 + kv0) + swsrc;
        GLD16(gv,                      (char*)Vs[buf] + w * 2048);
        GLD16(gv + (size_t)8 * L_ * 2, (char*)Vs[buf] + w * 2048 + 1024);
    };

    const float vb = verb_bias[layer * H_ + hh];
    const float* cb = case_bias + ((size_t)layer * H_ + hh) * (C_ * C_);
    for (int idx = t; idx < 9 * 512; idx += 256) {
        const int ci = idx >> 9, kv = idx & 511;
        const int cj = case_ids[b * L_ + kv];
        Bia[ci][kv] = (__bf16)(cb[ci * C_ + cj] + (cj == 8 ? vb : 0.f)
                               - 10000.f * (1.f - (float)amask[b * L_ + kv]));
    }
    __syncthreads();     // Bia visible (drains prologue loads once)

    stage(0, 0);         // tile-0 prefetch, rides across raw barriers below

    const int qloc = w * 16 + lq;
    const int qrow = qc * 64 + qloc;
    const int ci_q = case_ids[b * L_ + qrow];
    const __hip_bfloat16* qp = Q + ((size_t)b * L_ + qrow) * D_ + hh * HD_;
    const bf16x8 qf0 = *(const bf16x8*)(qp + lg * 8);
    const bf16x8 qf1 = *(const bf16x8*)(qp + 32 + lg * 8);

    float m_run = -1e30f, l_run = 0.f;
    f32x4 o[4] = {};
    const int ntiles = qc + 1;
    int cur = 0;

    for (int kt = 0; kt < ntiles; ++kt) {
        if (kt) __builtin_amdgcn_s_barrier();   // prev reads done before re-stage
        if (kt + 1 < ntiles) {
            stage(cur ^ 1, (kt + 1) * 64);
            asm volatile("s_waitcnt vmcnt(4)" ::: "memory");   // own stage(kt) done
        } else {
            asm volatile("s_waitcnt vmcnt(0)" ::: "memory");
        }
        __builtin_amdgcn_s_barrier();           // all waves' stage(kt) visible
        __builtin_amdgcn_sched_barrier(0);

        const char* kb  = (const char*)Ks[cur];
        const char* vb2 = (const char*)Vs[cur];

        f32x4 s[4] = {};
        __builtin_amdgcn_s_setprio(1);
#pragma unroll
        for (int c = 0; c < 4; ++c) {
            const bf16x8 ka = *(const bf16x8*)(kb + (16 * c + lq) * 128 + ((lg ^ swz) << 4));
            s[c] = MFMA16(ka, qf0, s[c]);
            const bf16x8 kc = *(const bf16x8*)(kb + (16 * c + lq) * 128 + (((4 + lg) ^ swz) << 4));
            s[c] = MFMA16(kc, qf1, s[c]);
        }
        __builtin_amdgcn_s_setprio(0);

        const __bf16* brow = &Bia[ci_q][kt * 64];
        const bool dtile = (kt == qc);
        float xs[16];
#pragma unroll
        for (int c = 0; c < 4; ++c) {
            const bf16x4 bb = *(const bf16x4*)(brow + 16 * c + lg * 4);
#pragma unroll
            for (int r = 0; r < 4; ++r) {
                const int kvl = 16 * c + lg * 4 + r;
                float v = s[c][r] * 0.125f + (float)bb[r];
                xs[4 * c + r] = (dtile && (kvl > qloc)) ? -1e9f : v;
            }
        }

        float a0 = fmaxf(fmaxf(xs[0], xs[1]),  fmaxf(xs[2], xs[3]));
        float a1 = fmaxf(fmaxf(xs[4], xs[5]),  fmaxf(xs[6], xs[7]));
        float a2 = fmaxf(fmaxf(xs[8], xs[9]),  fmaxf(xs[10], xs[11]));
        float a3 = fmaxf(fmaxf(xs[12], xs[13]), fmaxf(xs[14], xs[15]));
        float pmax = fmaxf(fmaxf(a0, a1), fmaxf(a2, a3));
        pmax = fmaxf(pmax, __shfl_xor(pmax, 16, 64));
        pmax = fmaxf(pmax, __shfl_xor(pmax, 32, 64));

        const float mnew = fmaxf(m_run, pmax);
        const float corr = __expf(m_run - mnew);
        float p[16], ps0 = 0.f, ps1 = 0.f;
#pragma unroll
        for (int j = 0; j < 16; j += 2) {
            p[j]     = __expf(xs[j] - mnew);     ps0 += p[j];
            p[j + 1] = __expf(xs[j + 1] - mnew); ps1 += p[j + 1];
        }
        float ps = ps0 + ps1;
        ps += __shfl_xor(ps, 16, 64);
        ps += __shfl_xor(ps, 32, 64);
        l_run = l_run * corr + ps;
        m_run = mnew;

        float cr[4];
#pragma unroll
        for (int r = 0; r < 4; ++r) cr[r] = __shfl(corr, lg * 4 + r, 64);
#pragma unroll
        for (int nt = 0; nt < 4; ++nt)
#pragma unroll
            for (int r = 0; r < 4; ++r) o[nt][r] *= cr[r];

        char* pw = (char*)Pl[w];
#pragma unroll
        for (int c = 0; c < 4; ++c) {
            bf16x4 pv;
#pragma unroll
            for (int r = 0; r < 4; ++r) pv[r] = (__bf16)p[4 * c + r];
            const int slot = (2 * c + (lg >> 1)) ^ swz;
            *(bf16x4*)(pw + lq * 128 + (slot << 4) + ((lg & 1) << 3)) = pv;
        }

        __builtin_amdgcn_s_setprio(1);
#pragma unroll
        for (int hf = 0; hf < 2; ++hf) {
            const bf16x8 pf = *(const bf16x8*)(pw + lq * 128 + (((hf * 4 + lg) ^ swz) << 4));
#pragma unroll
            for (int nt = 0; nt < 4; ++nt) {
                const bf16x8 vf = *(const bf16x8*)(vb2 + (nt * 16 + lq) * 128
                                                   + (((hf * 4 + lg) ^ swz) << 4));
                o[nt] = MFMA16(pf, vf, o[nt]);
            }
        }
        __builtin_amdgcn_s_setprio(0);

        cur ^= 1;
    }

    const float inv = 1.f / l_run;
    float ir[4];
#pragma unroll
    for (int r = 0; r < 4; ++r) ir[r] = __shfl(inv, lg * 4 + r, 64);
    __hip_bfloat16* op = Out + ((size_t)b * L_ + qc * 64 + w * 16) * D_ + hh * HD_;
#pragma unroll
    for (int nt = 0; nt < 4; ++nt)
#pragma unroll
        for (int r = 0; r < 4; ++r)
            op[(size_t)(lg * 4 + r) * D_ + nt * 16 + lq] = __float2bfloat16(o[nt][r] * ir[r]);
}

// ---------------------------------------------------------------------------
extern "C" void kernel_launch(void* const* d_in, const int* in_sizes, int n_in,
                              void* d_out, int out_size, void* d_ws, size_t ws_size,
                              hipStream_t stream)
{
    const float* x_in  = (const float*)d_in[0];
    const int*   cids  = (const int*)  d_in[1];
    const int*   amask = (const int*)  d_in[2];
    const float* Wq = (const float*)d_in[3];
    const float* bq = (const float*)d_in[4];
    const float* Wk = (const float*)d_in[5];
    const float* bk = (const float*)d_in[6];
    const float* Wv = (const float*)d_in[7];
    const float* bv = (const float*)d_in[8];
    const float* Wo = (const float*)d_in[9];
    const float* bo = (const float*)d_in[10];
    const float* ln1g = (const float*)d_in[11];
    const float* ln1b = (const float*)d_in[12];
    const float* ln2g = (const float*)d_in[13];
    const float* ln2b = (const float*)d_in[14];
    const float* W1 = (const float*)d_in[15];
    const float* b1 = (const float*)d_in[16];
    const float* W2 = (const float*)d_in[17];
    const float* b2 = (const float*)d_in[18];
    const float* cbias = (const float*)d_in[19];
    const float* vbias = (const float*)d_in[20];
    const float* fng = (const float*)d_in[21];
    const float* fnb = (const float*)d_in[22];

    char* w = (char*)d_ws;
    float* x_ws = (float*)w;                 w += (size_t)MTOK * D_ * 4;
    __hip_bfloat16* hbuf = (__hip_bfloat16*)w; w += (size_t)MTOK * D_ * 2;
    __hip_bfloat16* qbuf = (__hip_bfloat16*)w; w += (size_t)MTOK * D_ * 2;
    __hip_bfloat16* kbuf = (__hip_bfloat16*)w; w += (size_t)MTOK * D_ * 2;
    __hip_bfloat16* vtb  = (__hip_bfloat16*)w; w += (size_t)MTOK * D_ * 2;
    __hip_bfloat16* ffb  = (__hip_bfloat16*)w; w += (size_t)MTOK * F_ * 2;
    __hip_bfloat16* WqkvT = (__hip_bfloat16*)w; w += (size_t)NL_ * 3 * D_ * D_ * 2;
    __hip_bfloat16* WoT  = (__hip_bfloat16*)w; w += (size_t)NL_ * D_ * D_ * 2;
    __hip_bfloat16* W1T  = (__hip_bfloat16*)w; w += (size_t)NL_ * D_ * F_ * 2;
    __hip_bfloat16* W2T  = (__hip_bfloat16*)w; w += (size_t)NL_ * D_ * F_ * 2;

    const size_t qkvZ = (size_t)3 * D_ * D_;
    const dim3 tb(32, 8);
    transpose_w<<<dim3(D_/32, D_/32, NL_), tb, 0, stream>>>(Wq, WqkvT,           D_, D_, qkvZ);
    transpose_w<<<dim3(D_/32, D_/32, NL_), tb, 0, stream>>>(Wk, WqkvT + D_*D_,   D_, D_, qkvZ);
    transpose_w<<<dim3(D_/32, D_/32, NL_), tb, 0, stream>>>(Wv, WqkvT + 2*D_*D_, D_, D_, qkvZ);
    transpose_w<<<dim3(D_/32, D_/32, NL_), tb, 0, stream>>>(Wo, WoT, D_, D_, (size_t)D_*D_);
    transpose_w<<<dim3(F_/32, D_/32, NL_), tb, 0, stream>>>(W1, W1T, D_, F_, (size_t)D_*F_);
    transpose_w<<<dim3(D_/32, F_/32, NL_), tb, 0, stream>>>(W2, W2T, F_, D_, (size_t)D_*F_);

    copy_f32x4<<<8192, 256, 0, stream>>>((const float4*)x_in, (float4*)x_ws,
                                         MTOK * D_ / 4);

    const dim3 gQKV(12, 64);   // BM=256: 64 m-blocks x 12 n-blocks = 768
    const dim3 gO(4, 128);     // BM=128: 128 x 4 = 512
    const dim3 gW1(16, 64);    // BM=256: 64 x 16 = 1024
    const dim3 gW2(4, 128);    // BM=128: 128 x 4 = 512

    for (int i = 0; i < NL_; ++i) {
        ln_kernel<__hip_bfloat16><<<MTOK/4, 256, 0, stream>>>(
            x_ws, ln1g + i * D_, ln1b + i * D_, hbuf);

        gemm_r5<4, 4><<<gQKV, 512, 0, stream>>>(hbuf, WqkvT + (size_t)i * qkvZ,
            bq + i*D_, bk + i*D_, bv + i*D_, qbuf, kbuf, vtb, nullptr, 512, D_);

        attn_kernel<<<dim3(B_ * H_, L_/64), 256, 0, stream>>>(
            qbuf, kbuf, vtb, hbuf, cids, amask, cbias, vbias, i);

        gemm_r5<1, 2><<<gO, 256, 0, stream>>>(hbuf, WoT + (size_t)i*D_*D_,
            bo + i*D_, nullptr, nullptr, x_ws, nullptr, nullptr, x_ws, D_, D_);

        ln_kernel<__hip_bfloat16><<<MTOK/4, 256, 0, stream>>>(
            x_ws, ln2g + i * D_, ln2b + i * D_, hbuf);

        gemm_r5<2, 4><<<gW1, 512, 0, stream>>>(hbuf, W1T + (size_t)i*D_*F_,
            b1 + i*F_, nullptr, nullptr, ffb, nullptr, nullptr, nullptr, F_, D_);

        gemm_r5<1, 2><<<gW2, 256, 0, stream>>>(ffb, W2T + (size_t)i*D_*F_,
            b2 + i*D_, nullptr, nullptr, x_ws, nullptr, nullptr, x_ws, D_, F_);
    }

    ln_kernel<float><<<MTOK/4, 256, 0, stream>>>(x_ws, fng, fnb, (float*)d_out);
}

// Round 7
// 1277.333 us; speedup vs baseline: 1.9303x; 1.0378x over previous
//
#include <hip/hip_runtime.h>
#include <hip/hip_bf16.h>

// Problem constants
#define B_   32
#define L_   512
#define D_   512
#define H_   8
#define NL_  6
#define F_   2048
#define C_   9
#define HD_  64
#define MTOK 16384   // B_*L_

typedef __bf16 bf16x8 __attribute__((ext_vector_type(8)));
typedef __bf16 bf16x4 __attribute__((ext_vector_type(4)));
typedef float  f32x4  __attribute__((ext_vector_type(4)));

#define MFMA16(a,b,c) __builtin_amdgcn_mfma_f32_16x16x32_bf16((a),(b),(c),0,0,0)
#define GLD16(g,l) __builtin_amdgcn_global_load_lds( \
    (const __attribute__((address_space(1))) void*)(g), \
    (__attribute__((address_space(3))) void*)(l), 16, 0, 0)

// ---------------------------------------------------------------------------
// Weight transpose + f32->bf16: in [z][K][N] f32 -> out [z-stride zso][N][K]
// ---------------------------------------------------------------------------
__global__ __launch_bounds__(256) void transpose_w(
    const float* __restrict__ in, __hip_bfloat16* __restrict__ out,
    int K, int N, size_t zso)
{
    __shared__ float t[32][33];
    const int z = blockIdx.z;
    const float* src = in + (size_t)z * K * N;
    __hip_bfloat16* dst = out + (size_t)z * zso;
    const int n0 = blockIdx.x * 32, k0 = blockIdx.y * 32;
    const int tx = threadIdx.x, ty = threadIdx.y;   // (32,8)
#pragma unroll
    for (int r = ty; r < 32; r += 8)
        t[r][tx] = src[(size_t)(k0 + r) * N + n0 + tx];
    __syncthreads();
#pragma unroll
    for (int r = ty; r < 32; r += 8)
        dst[(size_t)(n0 + r) * K + k0 + tx] = __float2bfloat16(t[tx][r]);
}

// ---------------------------------------------------------------------------
__global__ void copy_f32x4(const float4* __restrict__ in, float4* __restrict__ out, int n)
{
    int i = blockIdx.x * blockDim.x + threadIdx.x;
    if (i < n) out[i] = in[i];
}

// ---------------------------------------------------------------------------
// bias_build: tab[((l*B+b)*H+h)*9+ci][kv] = cbias[l][h][ci][cj(kv)]
//             + (cj==8)*verb[l][h] - 10000*(1-amask[b][kv])   (bf16)
// ---------------------------------------------------------------------------
__global__ __launch_bounds__(256) void bias_build(
    const int* __restrict__ case_ids, const int* __restrict__ amask,
    const float* __restrict__ cbias, const float* __restrict__ vbias,
    __hip_bfloat16* __restrict__ tab)
{
    const unsigned idx = blockIdx.x * 256 + threadIdx.x;   // < NL*B*H*9*512
    const int kv = idx & 511;
    unsigned r = idx >> 9;
    const int ci = r % 9; r /= 9;
    const int hh = r % H_; r /= H_;
    const int b = r % B_; const int l = r / B_;
    const int cj = case_ids[b * L_ + kv];
    const float v = cbias[(((size_t)l * H_ + hh) * C_ + ci) * C_ + cj]
                  + (cj == 8 ? vbias[l * H_ + hh] : 0.f)
                  - 10000.f * (1.f - (float)amask[b * L_ + kv]);
    tab[idx] = __float2bfloat16(v);
}

// ---------------------------------------------------------------------------
// LayerNorm: one wave per row (D=512 -> 8 f32/lane). OUT = bf16 or f32.
// ---------------------------------------------------------------------------
template <typename OUT>
__global__ __launch_bounds__(256) void ln_kernel(
    const float* __restrict__ x, const float* __restrict__ g,
    const float* __restrict__ be, OUT* __restrict__ out)
{
    const int row  = blockIdx.x * 4 + (threadIdx.x >> 6);
    const int lane = threadIdx.x & 63;
    const int c0   = lane * 8;
    const float* xr = x + (size_t)row * D_ + c0;
    float4 a = *(const float4*)xr;
    float4 c = *(const float4*)(xr + 4);
    float v[8] = {a.x, a.y, a.z, a.w, c.x, c.y, c.z, c.w};

    float s = 0.f;
#pragma unroll
    for (int j = 0; j < 8; ++j) s += v[j];
#pragma unroll
    for (int o = 1; o < 64; o <<= 1) s += __shfl_xor(s, o, 64);
    const float mu = s * (1.0f / D_);

    float s2 = 0.f;
#pragma unroll
    for (int j = 0; j < 8; ++j) { float d = v[j] - mu; s2 += d * d; }
#pragma unroll
    for (int o = 1; o < 64; o <<= 1) s2 += __shfl_xor(s2, o, 64);
    const float rs = rsqrtf(s2 * (1.0f / D_) + 1e-5f);

    float4 g0 = *(const float4*)(g + c0);
    float4 g1 = *(const float4*)(g + c0 + 4);
    float4 b0 = *(const float4*)(be + c0);
    float4 b1 = *(const float4*)(be + c0 + 4);
    float gg[8] = {g0.x, g0.y, g0.z, g0.w, g1.x, g1.y, g1.z, g1.w};
    float bb[8] = {b0.x, b0.y, b0.z, b0.w, b1.x, b1.y, b1.z, b1.w};

    if constexpr (sizeof(OUT) == 2) {
        bf16x8 o8;
#pragma unroll
        for (int j = 0; j < 8; ++j)
            o8[j] = (__bf16)((v[j] - mu) * rs * gg[j] + bb[j]);
        *(bf16x8*)((__hip_bfloat16*)out + (size_t)row * D_ + c0) = o8;
    } else {
        float* op = (float*)out + (size_t)row * D_ + c0;
        float4 r0, r1;
        r0.x = (v[0]-mu)*rs*gg[0]+bb[0]; r0.y = (v[1]-mu)*rs*gg[1]+bb[1];
        r0.z = (v[2]-mu)*rs*gg[2]+bb[2]; r0.w = (v[3]-mu)*rs*gg[3]+bb[3];
        r1.x = (v[4]-mu)*rs*gg[4]+bb[4]; r1.y = (v[5]-mu)*rs*gg[5]+bb[5];
        r1.z = (v[6]-mu)*rs*gg[6]+bb[6]; r1.w = (v[7]-mu)*rs*gg[7]+bb[7];
        *(float4*)op = r0; *(float4*)(op + 4) = r1;
    }
}

// fast branchless tanh-form GELU (max abs err ~2.5e-4 vs exact erf form)
__device__ __forceinline__ float gelu_tanh(float v)
{
    const float t2 = v * v;
    const float u  = v * (0.7978845608028654f + 0.0356774081363001f * t2);
    const float a  = __builtin_fabsf(u);
    const float e  = __expf(-2.0f * a);
    const float r  = __builtin_amdgcn_rcpf(1.0f + e);
    const float th = (1.0f - e) * r;               // |tanh(u)|
    return 0.5f * v + 0.5f * __builtin_fabsf(v) * th;
}

// ---------------------------------------------------------------------------
// gemm_r5: multi-block-overlap GEMM. C[M][N] = A[M][K] @ BT[N][K]^T + bias.
// BK=32, ring-3 LDS, counted vmcnt (never 0 mid-loop), one s_barrier per
// K-tile, setprio around the MFMA cluster. Per-wave 64x64 (FM=FN=4).
//   WM=4: BM=256 BN=128, 8 waves, LDS 72 KiB, 2 blocks/CU  [W1]
//   WM=2: BM=128 BN=128, 4 waves, LDS 48 KiB, 3 blocks/CU  [QKV, O, W2]
// EPI: 1 = f32 residual add (out0==Res); 2 = tanh-GELU -> bf16;
//      4 = fused QKV epilogue (out0=q, out1=k, out2=VT[b][d][l]).
// ---------------------------------------------------------------------------
template <int EPI, int WM>
__global__ __launch_bounds__(WM * 128, (WM == 4) ? 4 : 3) void gemm_r5(
    const __hip_bfloat16* __restrict__ A,
    const __hip_bfloat16* __restrict__ BT,
    const float* __restrict__ bias0, const float* __restrict__ bias1,
    const float* __restrict__ bias2,
    void* __restrict__ out0, void* __restrict__ out1, void* __restrict__ out2,
    const float* __restrict__ Res, int Ndim, int K)
{
    constexpr int THREADS = WM * 128;
    constexpr int BM = WM * 64;
    __shared__ __align__(16) __hip_bfloat16 As[3][BM * 32];
    __shared__ __align__(16) __hip_bfloat16 Bs[3][128 * 32];

    const int tid = threadIdx.x;
    const int w = tid >> 6, lane = tid & 63;
    const int lq = lane & 15, lg = lane >> 4;
    const int wm = w >> 1, wn = w & 1;
    const int RB = wm * 64, CB = wn * 64;

    // T1: bijective XCD swizzle (nwg % 8 == 0 for all launches here)
    const int gX = gridDim.x;
    const int nwg = gX * gridDim.y;
    int flat = blockIdx.y * gX + blockIdx.x;
    {
        const int qq = nwg >> 3, rr = nwg & 7;
        const int xcd = flat & 7, off = flat >> 3;
        flat = (xcd < rr ? xcd * (qq + 1) : rr * (qq + 1) + (xcd - rr) * qq) + off;
    }
    const int bx = flat % gX, by = flat / gX;
    const int m0 = by * BM, n0 = bx * 128;

    // ---- staging geometry (pre-swizzled source, linear LDS dest) ----
    const int rc = tid >> 2;
    const int sc = ((tid & 3) ^ ((rc >> 1) & 3)) * 8;
    const __hip_bfloat16* gA0 = A  + (size_t)(m0 + rc) * K + sc;
    const __hip_bfloat16* gB0 = BT + (size_t)(n0 + rc) * K + sc;

    auto STAGE = [&](int tt) {
        const size_t ko = (size_t)tt * 32;
        const int sl = tt % 3;
        char* ab = (char*)As[sl] + w * 1024;
        GLD16(gA0 + ko, ab);
        GLD16(gA0 + (size_t)(THREADS / 4) * K + ko, ab + THREADS * 16);
        char* bb = (char*)Bs[sl] + w * 1024;
        GLD16(gB0 + ko, bb);
        if constexpr (WM == 2)
            GLD16(gB0 + (size_t)64 * K + ko, bb + 4096);
    };

    // ---- fragment read offsets (bytes), chunk-swizzled ----
    const int rsw = (lq >> 1) & 3;
    const int aoff = (RB + lq) * 64 + ((lg ^ rsw) << 4);
    const int boff = (CB + lq) * 64 + ((lg ^ rsw) << 4);

    f32x4 acc[4][4] = {};
    const int NTt = K >> 5;

    STAGE(0); STAGE(1);

    for (int t = 0; t < NTt; ++t) {
        if (t + 1 < NTt) {
            if constexpr (WM == 4) asm volatile("s_waitcnt vmcnt(3)" ::: "memory");
            else                   asm volatile("s_waitcnt vmcnt(4)" ::: "memory");
        } else {
            asm volatile("s_waitcnt vmcnt(0)" ::: "memory");
        }
        __builtin_amdgcn_s_barrier();
        __builtin_amdgcn_sched_barrier(0);

        const char* ca = (const char*)As[t % 3];
        const char* cb = (const char*)Bs[t % 3];
        bf16x8 af[4], bf[4];
#pragma unroll
        for (int fm = 0; fm < 4; ++fm) af[fm] = *(const bf16x8*)(ca + aoff + fm * 1024);
#pragma unroll
        for (int fn = 0; fn < 4; ++fn) bf[fn] = *(const bf16x8*)(cb + boff + fn * 1024);

        if (t + 2 < NTt) STAGE(t + 2);   // slot (t+2)%3: freed by this barrier

        __builtin_amdgcn_s_setprio(1);
#pragma unroll
        for (int fm = 0; fm < 4; ++fm)
#pragma unroll
            for (int fn = 0; fn < 4; ++fn)
                acc[fm][fn] = MFMA16(af[fm], bf[fn], acc[fm][fn]);
        __builtin_amdgcn_s_setprio(0);
    }

    // ---- epilogue ----
    if constexpr (EPI == 4) {
        const int sec = n0 >> 9;                 // 0=q, 1=k, 2=v
        const int nb = (n0 & 511) + CB;
        const float* bp = sec == 0 ? bias0 : (sec == 1 ? bias1 : bias2);
        float bcol[4];
#pragma unroll
        for (int fn = 0; fn < 4; ++fn) bcol[fn] = bp[nb + fn * 16 + lq];
        if (sec < 2) {
            __hip_bfloat16* op = (__hip_bfloat16*)(sec == 0 ? out0 : out1);
#pragma unroll
            for (int fm = 0; fm < 4; ++fm)
#pragma unroll
                for (int fn = 0; fn < 4; ++fn)
#pragma unroll
                    for (int r = 0; r < 4; ++r) {
                        const int m = m0 + RB + fm * 16 + lg * 4 + r;
                        op[(size_t)m * 512 + nb + fn * 16 + lq] =
                            __float2bfloat16(acc[fm][fn][r] + bcol[fn]);
                    }
        } else {
            __hip_bfloat16* vp = (__hip_bfloat16*)out2;
            const int bb = m0 >> 9;
            const int l0 = (m0 & 511) + RB + lg * 4;
#pragma unroll
            for (int fm = 0; fm < 4; ++fm)
#pragma unroll
                for (int fn = 0; fn < 4; ++fn) {
                    bf16x4 pv;
#pragma unroll
                    for (int r = 0; r < 4; ++r)
                        pv[r] = (__bf16)(acc[fm][fn][r] + bcol[fn]);
                    *(bf16x4*)(vp + ((size_t)(bb * 512 + nb + fn * 16 + lq)) * 512
                               + l0 + fm * 16) = pv;
                }
        }
    } else {
        float bcol[4];
#pragma unroll
        for (int fn = 0; fn < 4; ++fn) bcol[fn] = bias0[n0 + CB + fn * 16 + lq];
#pragma unroll
        for (int fm = 0; fm < 4; ++fm)
#pragma unroll
            for (int fn = 0; fn < 4; ++fn) {
                const int n = n0 + CB + fn * 16 + lq;
#pragma unroll
                for (int r = 0; r < 4; ++r) {
                    const int m = m0 + RB + fm * 16 + lg * 4 + r;
                    float v = acc[fm][fn][r] + bcol[fn];
                    if constexpr (EPI == 1) {
                        float* Co = (float*)out0;
                        const size_t idx = (size_t)m * Ndim + n;
                        Co[idx] = Res[idx] + v;
                    } else {  // EPI == 2: tanh-GELU
                        ((__hip_bfloat16*)out0)[(size_t)m * Ndim + n] =
                            __float2bfloat16(gelu_tanh(v));
                    }
                }
            }
    }
}

// ---------------------------------------------------------------------------
// Flash attention, paired q-chunks: block handles qcA = blockIdx.y (0..3) and
// qcB = 7-qcA; both chunks consume the SAME staged K/V tiles (kt = 0..qcB).
// Uniform 9 tile-computes per block; grid (B*H, 4) = 1024 blocks, 40 KiB LDS
// -> 4 blocks/CU = one full round. Bias comes from the precomputed global
// table (prefetched per tile before the MFMAs).
// ---------------------------------------------------------------------------
__global__ __launch_bounds__(256, 4) void attn_kernel(
    const __hip_bfloat16* __restrict__ Q, const __hip_bfloat16* __restrict__ K,
    const __hip_bfloat16* __restrict__ VT, __hip_bfloat16* __restrict__ Out,
    const int* __restrict__ case_ids, const __hip_bfloat16* __restrict__ tab,
    int layer)
{
    __shared__ __align__(16) __bf16 Ks[2][64 * 64];   // 16 KiB
    __shared__ __align__(16) __bf16 Vs[2][64 * 64];   // 16 KiB
    __shared__ __align__(16) __bf16 Pl[4][16 * 64];   //  8 KiB

    const int bh = blockIdx.x;
    const int b = bh >> 3, hh = bh & 7;
    const int qcA = blockIdx.y;          // 0..3
    const int qcB = 7 - qcA;             // 7..4
    const int t = threadIdx.x;
    const int w = t >> 6, lane = t & 63;
    const int lq = lane & 15, lg = lane >> 4;
    const int swz = lq & 7;

    const int rA = w * 16 + (lane >> 3);
    const int swsrc = ((lane & 7) ^ (lane >> 3)) << 4;
    const __hip_bfloat16* kg0 = K  + ((size_t)b * L_ + rA) * D_ + hh * HD_;
    const __hip_bfloat16* vg0 = VT + ((size_t)b * D_ + hh * HD_ + rA) * L_;

    auto stage = [&](int buf, int kv0) {
        const char* gk = (const char*)(kg0 + (size_t)kv0 * D_) + swsrc;
        GLD16(gk,                      (char*)Ks[buf] + w * 2048);
        GLD16(gk + (size_t)8 * D_ * 2, (char*)Ks[buf] + w * 2048 + 1024);
        const char* gv = (const char*)(vg0 + kv0) + swsrc;
        GLD16(gv,                      (char*)Vs[buf] + w * 2048);
        GLD16(gv + (size_t)8 * L_ * 2, (char*)Vs[buf] + w * 2048 + 1024);
    };

    stage(0, 0);

    const int qloc = w * 16 + lq;
    const int qrowA = qcA * 64 + qloc;
    const int qrowB = qcB * 64 + qloc;
    const size_t tbase = (((size_t)layer * B_ + b) * H_ + hh) * C_;
    const __hip_bfloat16* ciqA = tab + (tbase + case_ids[b * L_ + qrowA]) * L_;
    const __hip_bfloat16* ciqB = tab + (tbase + case_ids[b * L_ + qrowB]) * L_;

    const __hip_bfloat16* qpA = Q + ((size_t)b * L_ + qrowA) * D_ + hh * HD_;
    const __hip_bfloat16* qpB = Q + ((size_t)b * L_ + qrowB) * D_ + hh * HD_;
    const bf16x8 qfA0 = *(const bf16x8*)(qpA + lg * 8);
    const bf16x8 qfA1 = *(const bf16x8*)(qpA + 32 + lg * 8);
    const bf16x8 qfB0 = *(const bf16x8*)(qpB + lg * 8);
    const bf16x8 qfB1 = *(const bf16x8*)(qpB + 32 + lg * 8);

    float mA = -1e30f, lA = 0.f, mB = -1e30f, lB = 0.f;
    f32x4 oA[4] = {}, oB[4] = {};
    int cur = 0;

    auto process = [&](const bf16x8 qf0, const bf16x8 qf1,
                       const __hip_bfloat16* ciq, int qcX,
                       float& m_run, float& l_run, f32x4* o,
                       const char* kb, const char* vb2, int kt) {
        // prefetch bias row (independent of MFMAs)
        bf16x4 bb[4];
#pragma unroll
        for (int c = 0; c < 4; ++c)
            bb[c] = *(const bf16x4*)(ciq + kt * 64 + 16 * c + lg * 4);

        f32x4 s[4] = {};
        __builtin_amdgcn_s_setprio(1);
#pragma unroll
        for (int c = 0; c < 4; ++c) {
            const bf16x8 ka = *(const bf16x8*)(kb + (16 * c + lq) * 128 + ((lg ^ swz) << 4));
            s[c] = MFMA16(ka, qf0, s[c]);
            const bf16x8 kc = *(const bf16x8*)(kb + (16 * c + lq) * 128 + (((4 + lg) ^ swz) << 4));
            s[c] = MFMA16(kc, qf1, s[c]);
        }
        __builtin_amdgcn_s_setprio(0);

        const bool dtile = (kt == qcX);
        float xs[16];
#pragma unroll
        for (int c = 0; c < 4; ++c)
#pragma unroll
            for (int r = 0; r < 4; ++r) {
                const int kvl = 16 * c + lg * 4 + r;
                float v = s[c][r] * 0.125f + (float)bb[c][r];
                xs[4 * c + r] = (dtile && (kvl > qloc)) ? -1e9f : v;
            }

        float a0 = fmaxf(fmaxf(xs[0], xs[1]),  fmaxf(xs[2], xs[3]));
        float a1 = fmaxf(fmaxf(xs[4], xs[5]),  fmaxf(xs[6], xs[7]));
        float a2 = fmaxf(fmaxf(xs[8], xs[9]),  fmaxf(xs[10], xs[11]));
        float a3 = fmaxf(fmaxf(xs[12], xs[13]), fmaxf(xs[14], xs[15]));
        float pmax = fmaxf(fmaxf(a0, a1), fmaxf(a2, a3));
        pmax = fmaxf(pmax, __shfl_xor(pmax, 16, 64));
        pmax = fmaxf(pmax, __shfl_xor(pmax, 32, 64));

        const float mnew = fmaxf(m_run, pmax);
        const float corr = __expf(m_run - mnew);
        float ps = 0.f;
#pragma unroll
        for (int j = 0; j < 16; ++j) { xs[j] = __expf(xs[j] - mnew); ps += xs[j]; }
        ps += __shfl_xor(ps, 16, 64);
        ps += __shfl_xor(ps, 32, 64);
        l_run = l_run * corr + ps;
        m_run = mnew;

        float cr[4];
#pragma unroll
        for (int r = 0; r < 4; ++r) cr[r] = __shfl(corr, lg * 4 + r, 64);
#pragma unroll
        for (int nt = 0; nt < 4; ++nt)
#pragma unroll
            for (int r = 0; r < 4; ++r) o[nt][r] *= cr[r];

        char* pw = (char*)Pl[w];
#pragma unroll
        for (int c = 0; c < 4; ++c) {
            bf16x4 pv;
#pragma unroll
            for (int r = 0; r < 4; ++r) pv[r] = (__bf16)xs[4 * c + r];
            const int slot = (2 * c + (lg >> 1)) ^ swz;
            *(bf16x4*)(pw + lq * 128 + (slot << 4) + ((lg & 1) << 3)) = pv;
        }

        __builtin_amdgcn_s_setprio(1);
#pragma unroll
        for (int hf = 0; hf < 2; ++hf) {
            const bf16x8 pf = *(const bf16x8*)(pw + lq * 128 + (((hf * 4 + lg) ^ swz) << 4));
#pragma unroll
            for (int nt = 0; nt < 4; ++nt) {
                const bf16x8 vf = *(const bf16x8*)(vb2 + (nt * 16 + lq) * 128
                                                   + (((hf * 4 + lg) ^ swz) << 4));
                o[nt] = MFMA16(pf, vf, o[nt]);
            }
        }
        __builtin_amdgcn_s_setprio(0);
    };

    for (int kt = 0; kt <= qcB; ++kt) {
        if (kt) __builtin_amdgcn_s_barrier();   // prev reads done before re-stage
        if (kt < qcB) {
            stage(cur ^ 1, (kt + 1) * 64);
            asm volatile("s_waitcnt vmcnt(4)" ::: "memory");   // own stage(kt) done
        } else {
            asm volatile("s_waitcnt vmcnt(0)" ::: "memory");
        }
        __builtin_amdgcn_s_barrier();           // all waves' stage(kt) visible
        __builtin_amdgcn_sched_barrier(0);

        const char* kb  = (const char*)Ks[cur];
        const char* vb2 = (const char*)Vs[cur];

        process(qfB0, qfB1, ciqB, qcB, mB, lB, oB, kb, vb2, kt);
        if (kt <= qcA)
            process(qfA0, qfA1, ciqA, qcA, mA, lA, oA, kb, vb2, kt);
        cur ^= 1;
    }

    auto writeout = [&](float l_run, f32x4* o, int qcX) {
        const float inv = 1.f / l_run;
        float ir[4];
#pragma unroll
        for (int r = 0; r < 4; ++r) ir[r] = __shfl(inv, lg * 4 + r, 64);
        __hip_bfloat16* op = Out + ((size_t)b * L_ + qcX * 64 + w * 16) * D_ + hh * HD_;
#pragma unroll
        for (int nt = 0; nt < 4; ++nt)
#pragma unroll
            for (int r = 0; r < 4; ++r)
                op[(size_t)(lg * 4 + r) * D_ + nt * 16 + lq] =
                    __float2bfloat16(o[nt][r] * ir[r]);
    };
    writeout(lA, oA, qcA);
    writeout(lB, oB, qcB);
}

// ---------------------------------------------------------------------------
extern "C" void kernel_launch(void* const* d_in, const int* in_sizes, int n_in,
                              void* d_out, int out_size, void* d_ws, size_t ws_size,
                              hipStream_t stream)
{
    const float* x_in  = (const float*)d_in[0];
    const int*   cids  = (const int*)  d_in[1];
    const int*   amask = (const int*)  d_in[2];
    const float* Wq = (const float*)d_in[3];
    const float* bq = (const float*)d_in[4];
    const float* Wk = (const float*)d_in[5];
    const float* bk = (const float*)d_in[6];
    const float* Wv = (const float*)d_in[7];
    const float* bv = (const float*)d_in[8];
    const float* Wo = (const float*)d_in[9];
    const float* bo = (const float*)d_in[10];
    const float* ln1g = (const float*)d_in[11];
    const float* ln1b = (const float*)d_in[12];
    const float* ln2g = (const float*)d_in[13];
    const float* ln2b = (const float*)d_in[14];
    const float* W1 = (const float*)d_in[15];
    const float* b1 = (const float*)d_in[16];
    const float* W2 = (const float*)d_in[17];
    const float* b2 = (const float*)d_in[18];
    const float* cbias = (const float*)d_in[19];
    const float* vbias = (const float*)d_in[20];
    const float* fng = (const float*)d_in[21];
    const float* fnb = (const float*)d_in[22];

    char* w = (char*)d_ws;
    float* x_ws = (float*)w;                 w += (size_t)MTOK * D_ * 4;
    __hip_bfloat16* hbuf = (__hip_bfloat16*)w; w += (size_t)MTOK * D_ * 2;
    __hip_bfloat16* qbuf = (__hip_bfloat16*)w; w += (size_t)MTOK * D_ * 2;
    __hip_bfloat16* kbuf = (__hip_bfloat16*)w; w += (size_t)MTOK * D_ * 2;
    __hip_bfloat16* vtb  = (__hip_bfloat16*)w; w += (size_t)MTOK * D_ * 2;
    __hip_bfloat16* ffb  = (__hip_bfloat16*)w; w += (size_t)MTOK * F_ * 2;
    __hip_bfloat16* WqkvT = (__hip_bfloat16*)w; w += (size_t)NL_ * 3 * D_ * D_ * 2;
    __hip_bfloat16* WoT  = (__hip_bfloat16*)w; w += (size_t)NL_ * D_ * D_ * 2;
    __hip_bfloat16* W1T  = (__hip_bfloat16*)w; w += (size_t)NL_ * D_ * F_ * 2;
    __hip_bfloat16* W2T  = (__hip_bfloat16*)w; w += (size_t)NL_ * D_ * F_ * 2;
    __hip_bfloat16* btab = (__hip_bfloat16*)w; w += (size_t)NL_ * B_ * H_ * C_ * L_ * 2;

    const size_t qkvZ = (size_t)3 * D_ * D_;
    const dim3 tb(32, 8);
    transpose_w<<<dim3(D_/32, D_/32, NL_), tb, 0, stream>>>(Wq, WqkvT,           D_, D_, qkvZ);
    transpose_w<<<dim3(D_/32, D_/32, NL_), tb, 0, stream>>>(Wk, WqkvT + D_*D_,   D_, D_, qkvZ);
    transpose_w<<<dim3(D_/32, D_/32, NL_), tb, 0, stream>>>(Wv, WqkvT + 2*D_*D_, D_, D_, qkvZ);
    transpose_w<<<dim3(D_/32, D_/32, NL_), tb, 0, stream>>>(Wo, WoT, D_, D_, (size_t)D_*D_);
    transpose_w<<<dim3(F_/32, D_/32, NL_), tb, 0, stream>>>(W1, W1T, D_, F_, (size_t)D_*F_);
    transpose_w<<<dim3(D_/32, F_/32, NL_), tb, 0, stream>>>(W2, W2T, F_, D_, (size_t)D_*F_);

    bias_build<<<(NL_ * B_ * H_ * C_ * L_) / 256, 256, 0, stream>>>(
        cids, amask, cbias, vbias, btab);

    copy_f32x4<<<8192, 256, 0, stream>>>((const float4*)x_in, (float4*)x_ws,
                                         MTOK * D_ / 4);

    const dim3 gQKV(12, 128);  // BM=128: 128 x 12 = 1536 blocks (3/CU, 2 rounds)
    const dim3 gO(4, 128);     // BM=128: 512 blocks
    const dim3 gW1(16, 64);    // BM=256: 1024 blocks (2/CU, 2 rounds)
    const dim3 gW2(4, 128);    // BM=128: 512 blocks

    for (int i = 0; i < NL_; ++i) {
        ln_kernel<__hip_bfloat16><<<MTOK/4, 256, 0, stream>>>(
            x_ws, ln1g + i * D_, ln1b + i * D_, hbuf);

        gemm_r5<4, 2><<<gQKV, 256, 0, stream>>>(hbuf, WqkvT + (size_t)i * qkvZ,
            bq + i*D_, bk + i*D_, bv + i*D_, qbuf, kbuf, vtb, nullptr, 512, D_);

        attn_kernel<<<dim3(B_ * H_, 4), 256, 0, stream>>>(
            qbuf, kbuf, vtb, hbuf, cids, btab, i);

        gemm_r5<1, 2><<<gO, 256, 0, stream>>>(hbuf, WoT + (size_t)i*D_*D_,
            bo + i*D_, nullptr, nullptr, x_ws, nullptr, nullptr, x_ws, D_, D_);

        ln_kernel<__hip_bfloat16><<<MTOK/4, 256, 0, stream>>>(
            x_ws, ln2g + i * D_, ln2b + i * D_, hbuf);

        gemm_r5<2, 4><<<gW1, 512, 0, stream>>>(hbuf, W1T + (size_t)i*D_*F_,
            b1 + i*F_, nullptr, nullptr, ffb, nullptr, nullptr, nullptr, F_, D_);

        gemm_r5<1, 2><<<gW2, 256, 0, stream>>>(ffb, W2T + (size_t)i*D_*F_,
            b2 + i*D_, nullptr, nullptr, x_ws, nullptr, nullptr, x_ws, D_, F_);
    }

    ln_kernel<float><<<MTOK/4, 256, 0, stream>>>(x_ws, fng, fnb, (float*)d_out);
}